// Round 4
// baseline (1661.666 us; speedup 1.0000x reference)
//
#include <hip/hip_runtime.h>
#include <stdint.h>

typedef unsigned short u16;
typedef unsigned int u32;

#define B_ 2
#define T_ 2048
#define C_ 2048
#define H_ 32
#define M_ (B_*T_)              /* 4096 rows */
static const size_t MC = (size_t)M_ * C_;   /* 8388608 */

typedef __attribute__((ext_vector_type(8))) short s16x8;
typedef __attribute__((ext_vector_type(4))) float f32x4;

__device__ __forceinline__ u16 f2bf(float f) {
  union { float f; u32 u; } v; v.f = f;
  u32 r = v.u + 0x7FFFu + ((v.u >> 16) & 1u);
  return (u16)(r >> 16);
}
__device__ __forceinline__ float bits2f(u32 u) {
  union { u32 u; float f; } v; v.u = u; return v.f;
}
__device__ __forceinline__ float bf2f(u16 h) { return bits2f(((u32)h) << 16); }
__device__ __forceinline__ float sigm(float x) { return 1.0f / (1.0f + expf(-x)); }

__device__ __forceinline__ float wsum64(float x) {
  x += __shfl_xor(x, 32);
  x += __shfl_xor(x, 16);
  x += __shfl_xor(x, 8);
  x += __shfl_xor(x, 4);
  x += __shfl_xor(x, 2);
  x += __shfl_xor(x, 1);
  return x;
}

#define GL2LDS(g, l) __builtin_amdgcn_global_load_lds( \
    (const __attribute__((address_space(1))) u32*)(g), \
    (__attribute__((address_space(3))) u32*)(l), 16, 0, 0)

/* ---------------- bf16 NT GEMM, 128x128 tile, BK=32 (m97 structure) ----------------
   C[M,N] = A[M,K] * B[N,K]^T ; A,B bf16 row-major (lda=ldb=K); C bf16 or fp32. */
template<bool BF16OUT>
__global__ void __launch_bounds__(256) gemm128(const u16* __restrict__ A, const u16* __restrict__ Bm,
                                               void* __restrict__ Cvp, int M, int N, int K) {
  __shared__ u16 As[128 * 32];
  __shared__ u16 Bs[128 * 32];
  const int tid = threadIdx.x;
  const int w = tid >> 6, l = tid & 63;
  const int wm = w >> 1, wn = w & 1;
  const int bm = blockIdx.x, bn = blockIdx.y;

  const int row0 = tid >> 2, kq0 = tid & 3;
  const u16* ag0 = A + (size_t)(bm * 128 + row0) * K + kq0 * 8;
  const u16* ag1 = ag0 + (size_t)64 * K;
  const u16* bg0 = Bm + (size_t)(bn * 128 + row0) * K + kq0 * 8;
  const u16* bg1 = bg0 + (size_t)64 * K;
  u16* al0 = &As[w * 512];
  u16* al1 = &As[2048 + w * 512];
  u16* bl0 = &Bs[w * 512];
  u16* bl1 = &Bs[2048 + w * 512];

  const int lrow = l & 15, lko = (l >> 4) * 8;
  const u16* Ars = &As[(wm * 64 + lrow) * 32 + lko];
  const u16* Brs = &Bs[(wn * 64 + lrow) * 32 + lko];

  f32x4 acc[4][4] = {};

  for (int k0 = 0; k0 < K; k0 += 32) {
    __syncthreads();
    GL2LDS(ag0, al0); GL2LDS(ag1, al1);
    GL2LDS(bg0, bl0); GL2LDS(bg1, bl1);
    ag0 += 32; ag1 += 32; bg0 += 32; bg1 += 32;
    __syncthreads();
    s16x8 af[4], bf[4];
#pragma unroll
    for (int m = 0; m < 4; ++m) af[m] = *(const s16x8*)(Ars + m * 16 * 32);
#pragma unroll
    for (int n = 0; n < 4; ++n) bf[n] = *(const s16x8*)(Brs + n * 16 * 32);
#pragma unroll
    for (int m = 0; m < 4; ++m)
#pragma unroll
      for (int n = 0; n < 4; ++n)
        acc[m][n] = __builtin_amdgcn_mfma_f32_16x16x32_bf16(af[m], bf[n], acc[m][n], 0, 0, 0);
  }

  const int crow0 = bm * 128 + wm * 64 + (l >> 4) * 4;
  const int ccol0 = bn * 128 + wn * 64 + (l & 15);
  if constexpr (BF16OUT) {
    u16* Cm = (u16*)Cvp;
#pragma unroll
    for (int m = 0; m < 4; ++m)
#pragma unroll
      for (int rr = 0; rr < 4; ++rr) {
        const int row = crow0 + m * 16 + rr;
        u16* cp = Cm + (size_t)row * N + ccol0;
#pragma unroll
        for (int n = 0; n < 4; ++n) cp[n * 16] = f2bf(acc[m][n][rr]);
      }
  } else {
    float* Cm = (float*)Cvp;
#pragma unroll
    for (int m = 0; m < 4; ++m)
#pragma unroll
      for (int rr = 0; rr < 4; ++rr) {
        const int row = crow0 + m * 16 + rr;
        float* cp = Cm + (size_t)row * N + ccol0;
#pragma unroll
        for (int n = 0; n < 4; ++n) cp[n * 16] = acc[m][n][rr];
      }
  }
}

/* ---------------- bf16 NT GEMM, 128x32 tile (small-N stage-1 LoRA GEMMs), fp32 out ---------------- */
__global__ void __launch_bounds__(256) gemm_bn32(const u16* __restrict__ A, const u16* __restrict__ Bm,
                                                 float* __restrict__ Cm, int M, int N, int K) {
  __shared__ u16 As[128 * 32];
  __shared__ u16 Bs[32 * 32];
  const int tid = threadIdx.x;
  const int w = tid >> 6, l = tid & 63;
  const int bm = blockIdx.x, bn = blockIdx.y;

  const int row0 = tid >> 2, kq0 = tid & 3;
  const u16* ag0 = A + (size_t)(bm * 128 + row0) * K + kq0 * 8;
  const u16* ag1 = ag0 + (size_t)64 * K;
  u16* al0 = &As[w * 512];
  u16* al1 = &As[2048 + w * 512];

  const int bc = (w & 1) * 64 + l;  /* chunk id for B staging (waves 0,1) */
  const u16* bg0 = Bm + (size_t)(bn * 32 + (bc >> 2)) * K + (bc & 3) * 8;
  u16* bl0 = &Bs[(w & 1) * 512];

  const int lrow = l & 15, lko = (l >> 4) * 8;
  const u16* Ars = &As[(w * 32 + lrow) * 32 + lko];
  const u16* Brs = &Bs[lrow * 32 + lko];

  f32x4 acc[2][2] = {};
  for (int k0 = 0; k0 < K; k0 += 32) {
    __syncthreads();
    GL2LDS(ag0, al0); GL2LDS(ag1, al1);
    if (w < 2) GL2LDS(bg0, bl0);
    ag0 += 32; ag1 += 32; bg0 += 32;
    __syncthreads();
    s16x8 af[2], bf[2];
    af[0] = *(const s16x8*)(Ars);
    af[1] = *(const s16x8*)(Ars + 16 * 32);
    bf[0] = *(const s16x8*)(Brs);
    bf[1] = *(const s16x8*)(Brs + 16 * 32);
#pragma unroll
    for (int m = 0; m < 2; ++m)
#pragma unroll
      for (int n = 0; n < 2; ++n)
        acc[m][n] = __builtin_amdgcn_mfma_f32_16x16x32_bf16(af[m], bf[n], acc[m][n], 0, 0, 0);
  }
  const int crow0 = bm * 128 + w * 32 + (l >> 4) * 4;
  const int ccol0 = bn * 32 + (l & 15);
#pragma unroll
  for (int m = 0; m < 2; ++m)
#pragma unroll
    for (int rr = 0; rr < 4; ++rr) {
      const int row = crow0 + m * 16 + rr;
      float* cp = Cm + (size_t)row * N + ccol0;
      cp[0] = acc[m][0][rr];
      cp[16] = acc[m][1][rr];
    }
}

/* ---------------- time-shift + 6 token mixes -> bf16 A matrices ---------------- */
__global__ void __launch_bounds__(256) prep_mix(const float* __restrict__ x,
    const float* __restrict__ mr, const float* __restrict__ mw, const float* __restrict__ mk,
    const float* __restrict__ mv, const float* __restrict__ ma, const float* __restrict__ mg,
    u16* __restrict__ xrb, u16* __restrict__ xwb, u16* __restrict__ xkb,
    u16* __restrict__ xvb, u16* __restrict__ xab, u16* __restrict__ xgb) {
  int gid = blockIdx.x * 256 + threadIdx.x;   /* 0 .. MC/8 */
  int row = gid >> 8;
  int col = (gid & 255) << 3;
  size_t base = (size_t)row * C_ + col;
  float xv[8], dx[8];
  *(float4*)&xv[0] = *(const float4*)(x + base);
  *(float4*)&xv[4] = *(const float4*)(x + base + 4);
  if ((row & (T_ - 1)) == 0) {
#pragma unroll
    for (int j = 0; j < 8; ++j) dx[j] = -xv[j];
  } else {
    float xp[8];
    *(float4*)&xp[0] = *(const float4*)(x + base - C_);
    *(float4*)&xp[4] = *(const float4*)(x + base - C_ + 4);
#pragma unroll
    for (int j = 0; j < 8; ++j) dx[j] = xp[j] - xv[j];
  }
#define EMIT(dst, mixp) { \
    float4 m0 = *(const float4*)(mixp + col); \
    float4 m1 = *(const float4*)(mixp + col + 4); \
    float o0 = xv[0] + dx[0] * m0.x, o1 = xv[1] + dx[1] * m0.y; \
    float o2 = xv[2] + dx[2] * m0.z, o3 = xv[3] + dx[3] * m0.w; \
    float o4 = xv[4] + dx[4] * m1.x, o5 = xv[5] + dx[5] * m1.y; \
    float o6 = xv[6] + dx[6] * m1.z, o7 = xv[7] + dx[7] * m1.w; \
    uint4 pk; \
    pk.x = (u32)f2bf(o0) | ((u32)f2bf(o1) << 16); \
    pk.y = (u32)f2bf(o2) | ((u32)f2bf(o3) << 16); \
    pk.z = (u32)f2bf(o4) | ((u32)f2bf(o5) << 16); \
    pk.w = (u32)f2bf(o6) | ((u32)f2bf(o7) << 16); \
    *(uint4*)(dst + base) = pk; }
  EMIT(xrb, mr) EMIT(xwb, mw) EMIT(xkb, mk) EMIT(xvb, mv) EMIT(xab, ma) EMIT(xgb, mg)
#undef EMIT
}

/* ---------------- fp32 -> bf16 (8 elems/thread) ---------------- */
__global__ void __launch_bounds__(256) convbf8(const float* __restrict__ in, u16* __restrict__ out, int n8) {
  int gid = blockIdx.x * 256 + threadIdx.x;
  if (gid >= n8) return;
  size_t b = (size_t)gid * 8;
  float4 a0 = *(const float4*)(in + b), a1 = *(const float4*)(in + b + 4);
  uint4 pk;
  pk.x = (u32)f2bf(a0.x) | ((u32)f2bf(a0.y) << 16);
  pk.y = (u32)f2bf(a0.z) | ((u32)f2bf(a0.w) << 16);
  pk.z = (u32)f2bf(a1.x) | ((u32)f2bf(a1.y) << 16);
  pk.w = (u32)f2bf(a1.z) | ((u32)f2bf(a1.w) << 16);
  *(uint4*)(out + b) = pk;
}

/* ---------------- transpose + bf16 convert: in[R][Cc] -> out[Cc][R] ---------------- */
__global__ void __launch_bounds__(256) tconvbf(const float* __restrict__ in, u16* __restrict__ out, int R, int Cc) {
  int gid = blockIdx.x * 256 + threadIdx.x;
  if (gid >= R * Cc) return;
  int i = gid % R, j = gid / R;
  out[gid] = f2bf(in[(size_t)i * Cc + j]);
}

/* ---------------- activation + bf16 convert (mode 0=tanh,1=id,2=sigmoid) ---------------- */
__global__ void __launch_bounds__(256) act_conv(const float* __restrict__ in, u16* __restrict__ out, int n, int mode) {
  int gid = blockIdx.x * 256 + threadIdx.x;
  if (gid >= n) return;
  float v = in[gid];
  if (mode == 0) v = tanhf(v);
  else if (mode == 2) v = sigm(v);
  out[gid] = f2bf(v);
}

/* ---------------- scan-prep: decay, kk-norm, k', v-blend, z, b, bonus ----------------
   In-place per-element updates (each thread owns idx; all reads precede writes). */
__global__ void __launch_bounds__(256) scan_prep(
    const u16* __restrict__ rb, u16* __restrict__ kb, u16* __restrict__ vb,
    const u16* __restrict__ dwb, u16* __restrict__ dab, u16* __restrict__ dvbb,
    const float* __restrict__ v_first,
    const float* __restrict__ a0, const float* __restrict__ v0, const float* __restrict__ w0,
    const float* __restrict__ k_k, const float* __restrict__ k_a, const float* __restrict__ r_k,
    u16* __restrict__ dec, u16* __restrict__ bonus) {
  int rh = blockIdx.x * 4 + (threadIdx.x >> 6);
  int n = threadIdx.x & 63;
  int h = rh & (H_ - 1);
  size_t idx = (size_t)rh * 64 + n;
  int c = h * 64 + n;
  float kv = bf2f(kb[idx]), dav = bf2f(dab[idx]), dwv = bf2f(dwb[idx]);
  float dvv = bf2f(dvbb[idx]), vv = bf2f(vb[idx]);
  float vf = v_first[idx], rv = bf2f(rb[idx]);
  float av = sigm(a0[c] + dav);
  float kkv = kv * k_k[c];
  float ss = wsum64(kkv * kkv);
  float kkn = kkv / fmaxf(sqrtf(ss), 1e-12f);
  float k2 = kv * (1.f + (av - 1.f) * k_a[c]);
  float w_ = w0[c] + dwv;
  float wl = -log1pf(expf(-w_)) - 0.5f;
  float decf = expf(-expf(wl));
  float sv = sigm(v0[c] + dvv);
  float v2 = vv + (vf - vv) * sv;
  float bp = wsum64(rv * k2 * r_k[c]);
  kb[idx] = f2bf(k2);
  vb[idx] = f2bf(v2);
  dab[idx] = f2bf(kkn * av);   /* b */
  dvbb[idx] = f2bf(-kkn);      /* z */
  dec[idx] = f2bf(decf);
  bonus[idx] = f2bf(bp * v2);
}

/* ---------------- RWKV7 sequential scan: 1 block per (b,h), 4 waves, row-parallel ----------------
   thread owns (row i, j-quarter q): S[i][16q..16q+16) in registers.
   All 6 arrays bf16 in LDS: 2 x ds_read_b128 per array per step; chained 2-shuffle reduces. */
__device__ __forceinline__ void unpk8(u32 a, u32 b, u32 c, u32 d, float* o) {
  o[0] = bits2f(a << 16); o[1] = bits2f(a & 0xffff0000u);
  o[2] = bits2f(b << 16); o[3] = bits2f(b & 0xffff0000u);
  o[4] = bits2f(c << 16); o[5] = bits2f(c & 0xffff0000u);
  o[6] = bits2f(d << 16); o[7] = bits2f(d & 0xffff0000u);
}

__global__ void __launch_bounds__(256) rwkv_scan(
    const u16* __restrict__ rb, const u16* __restrict__ decb, const u16* __restrict__ kb,
    const u16* __restrict__ vb, const u16* __restrict__ zb, const u16* __restrict__ bbuf,
    float* __restrict__ yb) {
  __shared__ alignas(16) u16 lds16[6 * 16 * 64];   /* [arr][step][n] bf16, 12 KiB */
  const int tid = threadIdx.x;
  const int w = tid >> 6, l = tid & 63;
  const int i = w * 16 + (l & 15);
  const int q = l >> 4;
  const int bb = blockIdx.x >> 5, h = blockIdx.x & (H_ - 1);
  const size_t headbase = ((size_t)bb * T_ * H_ + h) * 64;
  /* prefetch slot: 4 consecutive bf16 per thread per array */
  const int pt = tid >> 4;               /* step within chunk 0..15 */
  const int pn = (tid & 15) * 4;         /* n offset 0..60 */
  const size_t poff = headbase + (size_t)pt * C_ + pn;
  const int li = pt * 64 + pn;

  float S[16];
#pragma unroll
  for (int jj = 0; jj < 16; ++jj) S[jj] = 0.f;

  uint2 pr, pd, pk, pv, pz, pb;
  pr = *(const uint2*)(rb + poff);
  pd = *(const uint2*)(decb + poff);
  pk = *(const uint2*)(kb + poff);
  pv = *(const uint2*)(vb + poff);
  pz = *(const uint2*)(zb + poff);
  pb = *(const uint2*)(bbuf + poff);

  for (int ch = 0; ch < T_ / 16; ++ch) {
    __syncthreads();
    *(uint2*)&lds16[0 * 1024 + li] = pr;
    *(uint2*)&lds16[1 * 1024 + li] = pd;
    *(uint2*)&lds16[2 * 1024 + li] = pk;
    *(uint2*)&lds16[3 * 1024 + li] = pv;
    *(uint2*)&lds16[4 * 1024 + li] = pz;
    *(uint2*)&lds16[5 * 1024 + li] = pb;
    __syncthreads();
    if (ch + 1 < T_ / 16) {
      size_t o2 = poff + (size_t)(ch + 1) * 16 * C_;
      pr = *(const uint2*)(rb + o2);
      pd = *(const uint2*)(decb + o2);
      pk = *(const uint2*)(kb + o2);
      pv = *(const uint2*)(vb + o2);
      pz = *(const uint2*)(zb + o2);
      pb = *(const uint2*)(bbuf + o2);
    }
#pragma unroll
    for (int t = 0; t < 16; ++t) {
      const int tb = t * 64 + q * 16;   /* u16 index of this thread's 16-j slice */
      /* --- sa partial: z-slice, products, pairwise tree --- */
      float zf[16];
      {
        uint4 u0 = *(const uint4*)&lds16[4 * 1024 + tb];
        uint4 u1 = *(const uint4*)&lds16[4 * 1024 + tb + 8];
        unpk8(u0.x, u0.y, u0.z, u0.w, zf);
        unpk8(u1.x, u1.y, u1.z, u1.w, zf + 8);
      }
      float m[16];
#pragma unroll
      for (int e = 0; e < 16; ++e) m[e] = S[e] * zf[e];
#pragma unroll
      for (int st = 1; st < 16; st <<= 1)
#pragma unroll
        for (int e = 0; e < 16; e += 2 * st) m[e] = m[e] + m[e + st];
      float s1 = m[0] + __shfl_xor(m[0], 16);
      float sa = s1 + __shfl_xor(s1, 32);

      /* --- update + y --- */
      float df[16], bf_[16], kf[16], rf[16];
      {
        uint4 u0, u1;
        u0 = *(const uint4*)&lds16[1 * 1024 + tb];
        u1 = *(const uint4*)&lds16[1 * 1024 + tb + 8];
        unpk8(u0.x, u0.y, u0.z, u0.w, df);
        unpk8(u1.x, u1.y, u1.z, u1.w, df + 8);
        u0 = *(const uint4*)&lds16[5 * 1024 + tb];
        u1 = *(const uint4*)&lds16[5 * 1024 + tb + 8];
        unpk8(u0.x, u0.y, u0.z, u0.w, bf_);
        unpk8(u1.x, u1.y, u1.z, u1.w, bf_ + 8);
        u0 = *(const uint4*)&lds16[2 * 1024 + tb];
        u1 = *(const uint4*)&lds16[2 * 1024 + tb + 8];
        unpk8(u0.x, u0.y, u0.z, u0.w, kf);
        unpk8(u1.x, u1.y, u1.z, u1.w, kf + 8);
        u0 = *(const uint4*)&lds16[0 * 1024 + tb];
        u1 = *(const uint4*)&lds16[0 * 1024 + tb + 8];
        unpk8(u0.x, u0.y, u0.z, u0.w, rf);
        unpk8(u1.x, u1.y, u1.z, u1.w, rf + 8);
      }
      float vi = bf2f(lds16[3 * 1024 + t * 64 + i]);
      float yp[16];
#pragma unroll
      for (int e = 0; e < 16; ++e) {
        float sn = S[e] * df[e] + sa * bf_[e] + vi * kf[e];
        S[e] = sn;
        yp[e] = sn * rf[e];
      }
#pragma unroll
      for (int st = 1; st < 16; st <<= 1)
#pragma unroll
        for (int e = 0; e < 16; e += 2 * st) yp[e] = yp[e] + yp[e + st];
      float y1 = yp[0] + __shfl_xor(yp[0], 16);
      float y = y1 + __shfl_xor(y1, 32);
      if (q == 0) yb[headbase + (size_t)(ch * 16 + t) * C_ + i] = y;
    }
  }
}

/* ---------------- GroupNorm(64/head) + bonus + gate -> bf16 A for final GEMM ---------------- */
__global__ void __launch_bounds__(256) gn_gg(
    const float* __restrict__ yb, const u16* __restrict__ bonus, const u16* __restrict__ gb,
    const float* __restrict__ gnw, const float* __restrict__ gnb,
    u16* __restrict__ ggb) {
  int rh = blockIdx.x * 4 + (threadIdx.x >> 6);
  int n = threadIdx.x & 63;
  int h = rh & (H_ - 1);
  size_t idx = (size_t)rh * 64 + n;
  int c = h * 64 + n;
  float y = yb[idx];
  float mu = wsum64(y) * (1.f / 64.f);
  float d = y - mu;
  float var = wsum64(d * d) * (1.f / 64.f);
  float yn = d * rsqrtf(var + 6.4e-4f) * gnw[c] + gnb[c];
  ggb[idx] = f2bf((yn + bf2f(bonus[idx])) * bf2f(gb[idx]));
}

extern "C" void kernel_launch(void* const* d_in, const int* in_sizes, int n_in,
                              void* d_out, int out_size, void* d_ws, size_t ws_size,
                              hipStream_t stream) {
  const float* x      = (const float*)d_in[0];
  const float* vfirst = (const float*)d_in[1];
  const float* x_r = (const float*)d_in[2];
  const float* x_w = (const float*)d_in[3];
  const float* x_k = (const float*)d_in[4];
  const float* x_v = (const float*)d_in[5];
  const float* x_a = (const float*)d_in[6];
  const float* x_g = (const float*)d_in[7];
  const float* w0  = (const float*)d_in[8];
  const float* w1  = (const float*)d_in[9];
  const float* w2  = (const float*)d_in[10];
  const float* a0  = (const float*)d_in[11];
  const float* a1  = (const float*)d_in[12];
  const float* a2  = (const float*)d_in[13];
  const float* v0  = (const float*)d_in[14];
  const float* v1  = (const float*)d_in[15];
  const float* v2  = (const float*)d_in[16];
  const float* g1  = (const float*)d_in[17];
  const float* g2  = (const float*)d_in[18];
  const float* k_k = (const float*)d_in[19];
  const float* k_a = (const float*)d_in[20];
  const float* r_k = (const float*)d_in[21];
  const float* W_r = (const float*)d_in[22];
  const float* W_k = (const float*)d_in[23];
  const float* W_v = (const float*)d_in[24];
  const float* W_o = (const float*)d_in[25];
  const float* gnw = (const float*)d_in[26];
  const float* gnb = (const float*)d_in[27];
  float* out = (float*)d_out;

  char* ws = (char*)d_ws;
  size_t off = 0;
  auto alloc = [&](size_t bytes) -> void* {
    void* p = ws + off;
    off += (bytes + 255) & ~(size_t)255;
    return p;
  };
  const size_t MCb2 = MC * 2;

  /* A-region: 6 contiguous 16MiB bf16 mix buffers, later reused */
  u16* xrb = (u16*)alloc(MCb2);   /* A0: xr -> dw_bf -> ggb            */
  u16* xwb = (u16*)alloc(MCb2);   /* A1: xw -> da_bf -> b_bf           */
  u16* xkb = (u16*)alloc(MCb2);   /* A2: xk -> dv_bf -> z_bf           */
  u16* xvb = (u16*)alloc(MCb2);   /* A3: xv -> g_bf                    */
  u16* xab = (u16*)alloc(MCb2);   /* A4: xa ┐                          */
  u16* xgb = (u16*)alloc(MCb2);   /* A5: xg ┘ -> yb fp32 (32MiB)       */
  u16* Wrb = (u16*)alloc((size_t)C_ * C_ * 2);
  u16* Wkb = (u16*)alloc((size_t)C_ * C_ * 2);
  u16* Wvb = (u16*)alloc((size_t)C_ * C_ * 2);
  u16* Wob = (u16*)alloc((size_t)C_ * C_ * 2);
  u16* w1t = (u16*)alloc((size_t)64 * C_ * 2);
  u16* a1t = (u16*)alloc((size_t)64 * C_ * 2);
  u16* v1t = (u16*)alloc((size_t)32 * C_ * 2);
  u16* g1t = (u16*)alloc((size_t)128 * C_ * 2);
  u16* w2t = (u16*)alloc((size_t)C_ * 64 * 2);
  u16* a2t = (u16*)alloc((size_t)C_ * 64 * 2);
  u16* v2t = (u16*)alloc((size_t)C_ * 32 * 2);
  u16* g2t = (u16*)alloc((size_t)C_ * 128 * 2);
  float* hw = (float*)alloc((size_t)M_ * 64 * 4);
  float* ha = (float*)alloc((size_t)M_ * 64 * 4);
  float* hv = (float*)alloc((size_t)M_ * 32 * 4);
  float* hg = (float*)alloc((size_t)M_ * 128 * 4);
  u16* hwb = (u16*)alloc((size_t)M_ * 64 * 2);
  u16* hab = (u16*)alloc((size_t)M_ * 64 * 2);
  u16* hvb = (u16*)alloc((size_t)M_ * 32 * 2);
  u16* hgb = (u16*)alloc((size_t)M_ * 128 * 2);
  u16* r_bf = (u16*)alloc(MCb2);            /* D0 */
  u16* k_bf = (u16*)alloc(MCb2);            /* D1: k -> k2 in place */
  u16* v_bf = (u16*)alloc(MCb2);            /* D2: v -> v2 in place */
  u16* dec  = (u16*)alloc(MCb2);            /* E0 (bf16 now) */
  u16* bonus  = (u16*)alloc(MCb2);          /* E1 */
  /* aliases (regions dead at write time; see schedule) */
  u16* dw_bf = xrb;
  u16* da_bf = xwb;   /* then b_bf in place */
  u16* dv_bf = xkb;   /* then z_bf in place */
  u16* g_bf  = xvb;
  float* yb  = (float*)xab;  /* spans xab+xgb = 32 MiB */
  u16* ggb   = xrb;          /* after dw_bf consumed   */
  (void)ws_size; (void)in_sizes; (void)n_in; (void)out_size;

  dim3 blk(256);

  /* weight conversion */
  convbf8<<<(C_ * C_ / 8 + 255) / 256, blk, 0, stream>>>(W_r, Wrb, C_ * C_ / 8);
  convbf8<<<(C_ * C_ / 8 + 255) / 256, blk, 0, stream>>>(W_k, Wkb, C_ * C_ / 8);
  convbf8<<<(C_ * C_ / 8 + 255) / 256, blk, 0, stream>>>(W_v, Wvb, C_ * C_ / 8);
  convbf8<<<(C_ * C_ / 8 + 255) / 256, blk, 0, stream>>>(W_o, Wob, C_ * C_ / 8);
  tconvbf<<<(C_ * 64 + 255) / 256, blk, 0, stream>>>(w1, w1t, C_, 64);
  tconvbf<<<(C_ * 64 + 255) / 256, blk, 0, stream>>>(a1, a1t, C_, 64);
  tconvbf<<<(C_ * 32 + 255) / 256, blk, 0, stream>>>(v1, v1t, C_, 32);
  tconvbf<<<(C_ * 128 + 255) / 256, blk, 0, stream>>>(g1, g1t, C_, 128);
  tconvbf<<<(C_ * 64 + 255) / 256, blk, 0, stream>>>(w2, w2t, 64, C_);
  tconvbf<<<(C_ * 64 + 255) / 256, blk, 0, stream>>>(a2, a2t, 64, C_);
  tconvbf<<<(C_ * 32 + 255) / 256, blk, 0, stream>>>(v2, v2t, 32, C_);
  tconvbf<<<(C_ * 128 + 255) / 256, blk, 0, stream>>>(g2, g2t, 128, C_);

  /* time-shift mixes, v_first passthrough */
  prep_mix<<<(int)(MC / 8 / 256), blk, 0, stream>>>(x, x_r, x_w, x_k, x_v, x_a, x_g,
                                                    xrb, xwb, xkb, xvb, xab, xgb);
  hipMemcpyAsync(out + MC, vfirst, MC * sizeof(float), hipMemcpyDeviceToDevice, stream);

  /* big GEMMs: r, k, v (bf16 out) */
  dim3 g128(M_ / 128, C_ / 128);
  gemm128<true><<<g128, blk, 0, stream>>>(xrb, Wrb, r_bf, M_, C_, C_);
  gemm128<true><<<g128, blk, 0, stream>>>(xkb, Wkb, k_bf, M_, C_, C_);
  gemm128<true><<<g128, blk, 0, stream>>>(xvb, Wvb, v_bf, M_, C_, C_);

  /* LoRA stage-1 (fp32 out) */
  gemm_bn32<<<dim3(M_ / 128, 2), blk, 0, stream>>>(xwb, w1t, hw, M_, 64, C_);
  gemm_bn32<<<dim3(M_ / 128, 2), blk, 0, stream>>>(xab, a1t, ha, M_, 64, C_);
  gemm_bn32<<<dim3(M_ / 128, 1), blk, 0, stream>>>(xvb, v1t, hv, M_, 32, C_);
  gemm_bn32<<<dim3(M_ / 128, 4), blk, 0, stream>>>(xgb, g1t, hg, M_, 128, C_);

  /* activations + bf16 */
  act_conv<<<(M_ * 64 + 255) / 256, blk, 0, stream>>>(hw, hwb, M_ * 64, 0);
  act_conv<<<(M_ * 64 + 255) / 256, blk, 0, stream>>>(ha, hab, M_ * 64, 1);
  act_conv<<<(M_ * 32 + 255) / 256, blk, 0, stream>>>(hv, hvb, M_ * 32, 1);
  act_conv<<<(M_ * 128 + 255) / 256, blk, 0, stream>>>(hg, hgb, M_ * 128, 2);

  /* LoRA stage-2 (bf16 out, into dead mix regions) */
  gemm128<true><<<g128, blk, 0, stream>>>(hwb, w2t, dw_bf, M_, C_, 64);
  gemm128<true><<<g128, blk, 0, stream>>>(hab, a2t, da_bf, M_, C_, 64);
  gemm128<true><<<g128, blk, 0, stream>>>(hvb, v2t, dv_bf, M_, C_, 32);
  gemm128<true><<<g128, blk, 0, stream>>>(hgb, g2t, g_bf, M_, C_, 128);

  /* scan inputs (in-place bf16) + dec bf16 + bonus bf16 */
  scan_prep<<<M_ * H_ / 4, blk, 0, stream>>>(r_bf, k_bf, v_bf, dw_bf, da_bf, dv_bf, vfirst,
                                             a0, v0, w0, k_k, k_a, r_k, dec, bonus);

  /* sequential scan: (r, dec, k, v, z, b) -> y */
  rwkv_scan<<<B_ * H_, blk, 0, stream>>>(r_bf, dec, k_bf, v_bf, dv_bf, da_bf, yb);

  /* GroupNorm + bonus + gate -> bf16 */
  gn_gg<<<M_ * H_ / 4, blk, 0, stream>>>(yb, bonus, g_bf, gnw, gnb, ggb);

  /* output projection (fp32 out) */
  gemm128<false><<<g128, blk, 0, stream>>>(ggb, Wob, out, M_, C_, C_);
}

// Round 5
// 1347.047 us; speedup vs baseline: 1.2336x; 1.2336x over previous
//
#include <hip/hip_runtime.h>
#include <stdint.h>

typedef unsigned short u16;
typedef unsigned int u32;

#define B_ 2
#define T_ 2048
#define C_ 2048
#define H_ 32
#define M_ (B_*T_)              /* 4096 rows */
static const size_t MC = (size_t)M_ * C_;   /* 8388608 */

typedef __attribute__((ext_vector_type(8))) short s16x8;
typedef __attribute__((ext_vector_type(4))) float f32x4;

__device__ __forceinline__ u16 f2bf(float f) {
  union { float f; u32 u; } v; v.f = f;
  u32 r = v.u + 0x7FFFu + ((v.u >> 16) & 1u);
  return (u16)(r >> 16);
}
__device__ __forceinline__ float bits2f(u32 u) {
  union { u32 u; float f; } v; v.u = u; return v.f;
}
__device__ __forceinline__ float bf2f(u16 h) { return bits2f(((u32)h) << 16); }
__device__ __forceinline__ float sigm(float x) { return 1.0f / (1.0f + expf(-x)); }

__device__ __forceinline__ float wsum64(float x) {
  x += __shfl_xor(x, 32);
  x += __shfl_xor(x, 16);
  x += __shfl_xor(x, 8);
  x += __shfl_xor(x, 4);
  x += __shfl_xor(x, 2);
  x += __shfl_xor(x, 1);
  return x;
}

#define GL2LDS(g, l) __builtin_amdgcn_global_load_lds( \
    (const __attribute__((address_space(1))) u32*)(g), \
    (__attribute__((address_space(3))) u32*)(l), 16, 0, 0)

/* ---------------- bf16 NT GEMM, 128x128 tile, BK=32 (m97 structure) ----------------
   C[M,N] = A[M,K] * B[N,K]^T ; A,B bf16 row-major (lda=ldb=K); C bf16 or fp32. */
template<bool BF16OUT>
__global__ void __launch_bounds__(256) gemm128(const u16* __restrict__ A, const u16* __restrict__ Bm,
                                               void* __restrict__ Cvp, int M, int N, int K) {
  __shared__ u16 As[128 * 32];
  __shared__ u16 Bs[128 * 32];
  const int tid = threadIdx.x;
  const int w = tid >> 6, l = tid & 63;
  const int wm = w >> 1, wn = w & 1;
  const int bm = blockIdx.x, bn = blockIdx.y;

  const int row0 = tid >> 2, kq0 = tid & 3;
  const u16* ag0 = A + (size_t)(bm * 128 + row0) * K + kq0 * 8;
  const u16* ag1 = ag0 + (size_t)64 * K;
  const u16* bg0 = Bm + (size_t)(bn * 128 + row0) * K + kq0 * 8;
  const u16* bg1 = bg0 + (size_t)64 * K;
  u16* al0 = &As[w * 512];
  u16* al1 = &As[2048 + w * 512];
  u16* bl0 = &Bs[w * 512];
  u16* bl1 = &Bs[2048 + w * 512];

  const int lrow = l & 15, lko = (l >> 4) * 8;
  const u16* Ars = &As[(wm * 64 + lrow) * 32 + lko];
  const u16* Brs = &Bs[(wn * 64 + lrow) * 32 + lko];

  f32x4 acc[4][4] = {};

  for (int k0 = 0; k0 < K; k0 += 32) {
    __syncthreads();
    GL2LDS(ag0, al0); GL2LDS(ag1, al1);
    GL2LDS(bg0, bl0); GL2LDS(bg1, bl1);
    ag0 += 32; ag1 += 32; bg0 += 32; bg1 += 32;
    __syncthreads();
    s16x8 af[4], bf[4];
#pragma unroll
    for (int m = 0; m < 4; ++m) af[m] = *(const s16x8*)(Ars + m * 16 * 32);
#pragma unroll
    for (int n = 0; n < 4; ++n) bf[n] = *(const s16x8*)(Brs + n * 16 * 32);
#pragma unroll
    for (int m = 0; m < 4; ++m)
#pragma unroll
      for (int n = 0; n < 4; ++n)
        acc[m][n] = __builtin_amdgcn_mfma_f32_16x16x32_bf16(af[m], bf[n], acc[m][n], 0, 0, 0);
  }

  const int crow0 = bm * 128 + wm * 64 + (l >> 4) * 4;
  const int ccol0 = bn * 128 + wn * 64 + (l & 15);
  if constexpr (BF16OUT) {
    u16* Cm = (u16*)Cvp;
#pragma unroll
    for (int m = 0; m < 4; ++m)
#pragma unroll
      for (int rr = 0; rr < 4; ++rr) {
        const int row = crow0 + m * 16 + rr;
        u16* cp = Cm + (size_t)row * N + ccol0;
#pragma unroll
        for (int n = 0; n < 4; ++n) cp[n * 16] = f2bf(acc[m][n][rr]);
      }
  } else {
    float* Cm = (float*)Cvp;
#pragma unroll
    for (int m = 0; m < 4; ++m)
#pragma unroll
      for (int rr = 0; rr < 4; ++rr) {
        const int row = crow0 + m * 16 + rr;
        float* cp = Cm + (size_t)row * N + ccol0;
#pragma unroll
        for (int n = 0; n < 4; ++n) cp[n * 16] = acc[m][n][rr];
      }
  }
}

/* ---------------- bf16 NT GEMM, 128x32 tile (small-N stage-1 LoRA GEMMs), fp32 out ---------------- */
__global__ void __launch_bounds__(256) gemm_bn32(const u16* __restrict__ A, const u16* __restrict__ Bm,
                                                 float* __restrict__ Cm, int M, int N, int K) {
  __shared__ u16 As[128 * 32];
  __shared__ u16 Bs[32 * 32];
  const int tid = threadIdx.x;
  const int w = tid >> 6, l = tid & 63;
  const int bm = blockIdx.x, bn = blockIdx.y;

  const int row0 = tid >> 2, kq0 = tid & 3;
  const u16* ag0 = A + (size_t)(bm * 128 + row0) * K + kq0 * 8;
  const u16* ag1 = ag0 + (size_t)64 * K;
  u16* al0 = &As[w * 512];
  u16* al1 = &As[2048 + w * 512];

  const int bc = (w & 1) * 64 + l;  /* chunk id for B staging (waves 0,1) */
  const u16* bg0 = Bm + (size_t)(bn * 32 + (bc >> 2)) * K + (bc & 3) * 8;
  u16* bl0 = &Bs[(w & 1) * 512];

  const int lrow = l & 15, lko = (l >> 4) * 8;
  const u16* Ars = &As[(w * 32 + lrow) * 32 + lko];
  const u16* Brs = &Bs[lrow * 32 + lko];

  f32x4 acc[2][2] = {};
  for (int k0 = 0; k0 < K; k0 += 32) {
    __syncthreads();
    GL2LDS(ag0, al0); GL2LDS(ag1, al1);
    if (w < 2) GL2LDS(bg0, bl0);
    ag0 += 32; ag1 += 32; bg0 += 32;
    __syncthreads();
    s16x8 af[2], bf[2];
    af[0] = *(const s16x8*)(Ars);
    af[1] = *(const s16x8*)(Ars + 16 * 32);
    bf[0] = *(const s16x8*)(Brs);
    bf[1] = *(const s16x8*)(Brs + 16 * 32);
#pragma unroll
    for (int m = 0; m < 2; ++m)
#pragma unroll
      for (int n = 0; n < 2; ++n)
        acc[m][n] = __builtin_amdgcn_mfma_f32_16x16x32_bf16(af[m], bf[n], acc[m][n], 0, 0, 0);
  }
  const int crow0 = bm * 128 + w * 32 + (l >> 4) * 4;
  const int ccol0 = bn * 32 + (l & 15);
#pragma unroll
  for (int m = 0; m < 2; ++m)
#pragma unroll
    for (int rr = 0; rr < 4; ++rr) {
      const int row = crow0 + m * 16 + rr;
      float* cp = Cm + (size_t)row * N + ccol0;
      cp[0] = acc[m][0][rr];
      cp[16] = acc[m][1][rr];
    }
}

/* ---------------- time-shift + 6 token mixes -> bf16 A matrices ---------------- */
__global__ void __launch_bounds__(256) prep_mix(const float* __restrict__ x,
    const float* __restrict__ mr, const float* __restrict__ mw, const float* __restrict__ mk,
    const float* __restrict__ mv, const float* __restrict__ ma, const float* __restrict__ mg,
    u16* __restrict__ xrb, u16* __restrict__ xwb, u16* __restrict__ xkb,
    u16* __restrict__ xvb, u16* __restrict__ xab, u16* __restrict__ xgb) {
  int gid = blockIdx.x * 256 + threadIdx.x;   /* 0 .. MC/8 */
  int row = gid >> 8;
  int col = (gid & 255) << 3;
  size_t base = (size_t)row * C_ + col;
  float xv[8], dx[8];
  *(float4*)&xv[0] = *(const float4*)(x + base);
  *(float4*)&xv[4] = *(const float4*)(x + base + 4);
  if ((row & (T_ - 1)) == 0) {
#pragma unroll
    for (int j = 0; j < 8; ++j) dx[j] = -xv[j];
  } else {
    float xp[8];
    *(float4*)&xp[0] = *(const float4*)(x + base - C_);
    *(float4*)&xp[4] = *(const float4*)(x + base - C_ + 4);
#pragma unroll
    for (int j = 0; j < 8; ++j) dx[j] = xp[j] - xv[j];
  }
#define EMIT(dst, mixp) { \
    float4 m0 = *(const float4*)(mixp + col); \
    float4 m1 = *(const float4*)(mixp + col + 4); \
    float o0 = xv[0] + dx[0] * m0.x, o1 = xv[1] + dx[1] * m0.y; \
    float o2 = xv[2] + dx[2] * m0.z, o3 = xv[3] + dx[3] * m0.w; \
    float o4 = xv[4] + dx[4] * m1.x, o5 = xv[5] + dx[5] * m1.y; \
    float o6 = xv[6] + dx[6] * m1.z, o7 = xv[7] + dx[7] * m1.w; \
    uint4 pk; \
    pk.x = (u32)f2bf(o0) | ((u32)f2bf(o1) << 16); \
    pk.y = (u32)f2bf(o2) | ((u32)f2bf(o3) << 16); \
    pk.z = (u32)f2bf(o4) | ((u32)f2bf(o5) << 16); \
    pk.w = (u32)f2bf(o6) | ((u32)f2bf(o7) << 16); \
    *(uint4*)(dst + base) = pk; }
  EMIT(xrb, mr) EMIT(xwb, mw) EMIT(xkb, mk) EMIT(xvb, mv) EMIT(xab, ma) EMIT(xgb, mg)
#undef EMIT
}

/* ---------------- fp32 -> bf16 (8 elems/thread) ---------------- */
__global__ void __launch_bounds__(256) convbf8(const float* __restrict__ in, u16* __restrict__ out, int n8) {
  int gid = blockIdx.x * 256 + threadIdx.x;
  if (gid >= n8) return;
  size_t b = (size_t)gid * 8;
  float4 a0 = *(const float4*)(in + b), a1 = *(const float4*)(in + b + 4);
  uint4 pk;
  pk.x = (u32)f2bf(a0.x) | ((u32)f2bf(a0.y) << 16);
  pk.y = (u32)f2bf(a0.z) | ((u32)f2bf(a0.w) << 16);
  pk.z = (u32)f2bf(a1.x) | ((u32)f2bf(a1.y) << 16);
  pk.w = (u32)f2bf(a1.z) | ((u32)f2bf(a1.w) << 16);
  *(uint4*)(out + b) = pk;
}

/* ---------------- transpose + bf16 convert: in[R][Cc] -> out[Cc][R] ---------------- */
__global__ void __launch_bounds__(256) tconvbf(const float* __restrict__ in, u16* __restrict__ out, int R, int Cc) {
  int gid = blockIdx.x * 256 + threadIdx.x;
  if (gid >= R * Cc) return;
  int i = gid % R, j = gid / R;
  out[gid] = f2bf(in[(size_t)i * Cc + j]);
}

/* ---------------- activation + bf16 convert (mode 0=tanh,1=id,2=sigmoid) ---------------- */
__global__ void __launch_bounds__(256) act_conv(const float* __restrict__ in, u16* __restrict__ out, int n, int mode) {
  int gid = blockIdx.x * 256 + threadIdx.x;
  if (gid >= n) return;
  float v = in[gid];
  if (mode == 0) v = tanhf(v);
  else if (mode == 2) v = sigm(v);
  out[gid] = f2bf(v);
}

/* ---------------- scan-prep: decay, kk-norm, k', v-blend, z, b, bonus ----------------
   In-place per-element updates (each thread owns idx; all reads precede writes).
   dec stays fp32 (bf16 decay costs ~0.06 absmax). */
__global__ void __launch_bounds__(256) scan_prep(
    const u16* __restrict__ rb, u16* __restrict__ kb, u16* __restrict__ vb,
    const u16* __restrict__ dwb, u16* __restrict__ dab, u16* __restrict__ dvbb,
    const float* __restrict__ v_first,
    const float* __restrict__ a0, const float* __restrict__ v0, const float* __restrict__ w0,
    const float* __restrict__ k_k, const float* __restrict__ k_a, const float* __restrict__ r_k,
    float* __restrict__ dec, u16* __restrict__ bonus) {
  int rh = blockIdx.x * 4 + (threadIdx.x >> 6);
  int n = threadIdx.x & 63;
  int h = rh & (H_ - 1);
  size_t idx = (size_t)rh * 64 + n;
  int c = h * 64 + n;
  float kv = bf2f(kb[idx]), dav = bf2f(dab[idx]), dwv = bf2f(dwb[idx]);
  float dvv = bf2f(dvbb[idx]), vv = bf2f(vb[idx]);
  float vf = v_first[idx], rv = bf2f(rb[idx]);
  float av = sigm(a0[c] + dav);
  float kkv = kv * k_k[c];
  float ss = wsum64(kkv * kkv);
  float kkn = kkv / fmaxf(sqrtf(ss), 1e-12f);
  float k2 = kv * (1.f + (av - 1.f) * k_a[c]);
  float w_ = w0[c] + dwv;
  float wl = -log1pf(expf(-w_)) - 0.5f;
  float decf = expf(-expf(wl));
  float sv = sigm(v0[c] + dvv);
  float v2 = vv + (vf - vv) * sv;
  float bp = wsum64(rv * k2 * r_k[c]);
  kb[idx] = f2bf(k2);
  vb[idx] = f2bf(v2);
  dab[idx] = f2bf(kkn * av);   /* b */
  dvbb[idx] = f2bf(-kkn);      /* z */
  dec[idx] = decf;
  bonus[idx] = f2bf(bp * v2);
}

/* ---------------- RWKV7 sequential scan: 4 blocks per (b,h), 16 rows each ----------------
   256 blocks x 64 threads (1 wave). Lane = (row il = l&15, j-quarter q = l>>4).
   fp32 LDS (padded rows), b128 reads, pairwise trees, 3-parallel-shuffle reduces. */
__device__ __forceinline__ void unpk8(u32 a, u32 b, u32 c, u32 d, float* o) {
  o[0] = bits2f(a << 16); o[1] = bits2f(a & 0xffff0000u);
  o[2] = bits2f(b << 16); o[3] = bits2f(b & 0xffff0000u);
  o[4] = bits2f(c << 16); o[5] = bits2f(c & 0xffff0000u);
  o[6] = bits2f(d << 16); o[7] = bits2f(d & 0xffff0000u);
}

__global__ void __launch_bounds__(64) rwkv_scan(
    const u16* __restrict__ rb, const float* __restrict__ decb, const u16* __restrict__ kb,
    const u16* __restrict__ vb, const u16* __restrict__ zb, const u16* __restrict__ bbuf,
    float* __restrict__ yb) {
  __shared__ float Lr[16][68], Ld[16][68], Lk[16][68], Lz[16][68], Lb[16][68];
  __shared__ float Lv[16][20];
  const int tid = threadIdx.x;           /* 0..63 */
  const int il = tid & 15;               /* local row */
  const int q = tid >> 4;                /* j-quarter */
  const int bh = blockIdx.x >> 2;        /* 0..63 */
  const int rblk = blockIdx.x & 3;
  const int bbx = bh >> 5, h = bh & 31;
  const int i0 = rblk * 16;
  const size_t headbase = ((size_t)bbx * T_ * H_ + h) * 64;

  /* staging slot: thread loads 16 elems of one step for shared arrays, 4 v-elems */
  const int pt = tid >> 2;               /* step 0..15 */
  const int pc = (tid & 3) * 16;         /* col base */
  const size_t poff = headbase + (size_t)pt * C_ + pc;
  const size_t voff = headbase + (size_t)pt * C_ + i0 + (tid & 3) * 4;

  float S[16];
#pragma unroll
  for (int e = 0; e < 16; ++e) S[e] = 0.f;

  uint4 pr0, pr1, pk0, pk1, pz0, pz1, pb0, pb1;
  float4 pd0, pd1, pd2, pd3;
  uint2 pv;
  pr0 = *(const uint4*)(rb + poff);   pr1 = *(const uint4*)(rb + poff + 8);
  pk0 = *(const uint4*)(kb + poff);   pk1 = *(const uint4*)(kb + poff + 8);
  pz0 = *(const uint4*)(zb + poff);   pz1 = *(const uint4*)(zb + poff + 8);
  pb0 = *(const uint4*)(bbuf + poff); pb1 = *(const uint4*)(bbuf + poff + 8);
  pd0 = *(const float4*)(decb + poff);     pd1 = *(const float4*)(decb + poff + 4);
  pd2 = *(const float4*)(decb + poff + 8); pd3 = *(const float4*)(decb + poff + 12);
  pv  = *(const uint2*)(vb + voff);

  for (int ch = 0; ch < T_ / 16; ++ch) {
    __syncthreads();
    {
      float f[16];
      unpk8(pr0.x, pr0.y, pr0.z, pr0.w, f); unpk8(pr1.x, pr1.y, pr1.z, pr1.w, f + 8);
      *(float4*)&Lr[pt][pc + 0] = *(float4*)&f[0];  *(float4*)&Lr[pt][pc + 4] = *(float4*)&f[4];
      *(float4*)&Lr[pt][pc + 8] = *(float4*)&f[8];  *(float4*)&Lr[pt][pc + 12] = *(float4*)&f[12];
      unpk8(pk0.x, pk0.y, pk0.z, pk0.w, f); unpk8(pk1.x, pk1.y, pk1.z, pk1.w, f + 8);
      *(float4*)&Lk[pt][pc + 0] = *(float4*)&f[0];  *(float4*)&Lk[pt][pc + 4] = *(float4*)&f[4];
      *(float4*)&Lk[pt][pc + 8] = *(float4*)&f[8];  *(float4*)&Lk[pt][pc + 12] = *(float4*)&f[12];
      unpk8(pz0.x, pz0.y, pz0.z, pz0.w, f); unpk8(pz1.x, pz1.y, pz1.z, pz1.w, f + 8);
      *(float4*)&Lz[pt][pc + 0] = *(float4*)&f[0];  *(float4*)&Lz[pt][pc + 4] = *(float4*)&f[4];
      *(float4*)&Lz[pt][pc + 8] = *(float4*)&f[8];  *(float4*)&Lz[pt][pc + 12] = *(float4*)&f[12];
      unpk8(pb0.x, pb0.y, pb0.z, pb0.w, f); unpk8(pb1.x, pb1.y, pb1.z, pb1.w, f + 8);
      *(float4*)&Lb[pt][pc + 0] = *(float4*)&f[0];  *(float4*)&Lb[pt][pc + 4] = *(float4*)&f[4];
      *(float4*)&Lb[pt][pc + 8] = *(float4*)&f[8];  *(float4*)&Lb[pt][pc + 12] = *(float4*)&f[12];
      *(float4*)&Ld[pt][pc + 0] = pd0;  *(float4*)&Ld[pt][pc + 4] = pd1;
      *(float4*)&Ld[pt][pc + 8] = pd2;  *(float4*)&Ld[pt][pc + 12] = pd3;
      float g[4];
      g[0] = bits2f(pv.x << 16); g[1] = bits2f(pv.x & 0xffff0000u);
      g[2] = bits2f(pv.y << 16); g[3] = bits2f(pv.y & 0xffff0000u);
      *(float4*)&Lv[pt][(tid & 3) * 4] = *(float4*)&g[0];
    }
    __syncthreads();
    if (ch + 1 < T_ / 16) {
      size_t o2 = poff + (size_t)(ch + 1) * 16 * C_;
      size_t v2 = voff + (size_t)(ch + 1) * 16 * C_;
      pr0 = *(const uint4*)(rb + o2);   pr1 = *(const uint4*)(rb + o2 + 8);
      pk0 = *(const uint4*)(kb + o2);   pk1 = *(const uint4*)(kb + o2 + 8);
      pz0 = *(const uint4*)(zb + o2);   pz1 = *(const uint4*)(zb + o2 + 8);
      pb0 = *(const uint4*)(bbuf + o2); pb1 = *(const uint4*)(bbuf + o2 + 8);
      pd0 = *(const float4*)(decb + o2);     pd1 = *(const float4*)(decb + o2 + 4);
      pd2 = *(const float4*)(decb + o2 + 8); pd3 = *(const float4*)(decb + o2 + 12);
      pv  = *(const uint2*)(vb + v2);
    }
#pragma unroll
    for (int t = 0; t < 16; ++t) {
      const int jb = q * 16;
      /* --- sa partial: z-slice, products, pairwise tree, 3 parallel shuffles --- */
      float zf[16];
      *(float4*)&zf[0]  = *(const float4*)&Lz[t][jb + 0];
      *(float4*)&zf[4]  = *(const float4*)&Lz[t][jb + 4];
      *(float4*)&zf[8]  = *(const float4*)&Lz[t][jb + 8];
      *(float4*)&zf[12] = *(const float4*)&Lz[t][jb + 12];
      float m[16];
#pragma unroll
      for (int e = 0; e < 16; ++e) m[e] = S[e] * zf[e];
#pragma unroll
      for (int st = 1; st < 16; st <<= 1)
#pragma unroll
        for (int e = 0; e < 16; e += 2 * st) m[e] = m[e] + m[e + st];
      float s = m[0];
      float sa = (s + __shfl_xor(s, 16)) + (__shfl_xor(s, 32) + __shfl_xor(s, 48));

      /* --- update + y --- */
      float df[16], bf_[16], kf[16], rf[16];
      *(float4*)&df[0]  = *(const float4*)&Ld[t][jb + 0];
      *(float4*)&df[4]  = *(const float4*)&Ld[t][jb + 4];
      *(float4*)&df[8]  = *(const float4*)&Ld[t][jb + 8];
      *(float4*)&df[12] = *(const float4*)&Ld[t][jb + 12];
      *(float4*)&bf_[0]  = *(const float4*)&Lb[t][jb + 0];
      *(float4*)&bf_[4]  = *(const float4*)&Lb[t][jb + 4];
      *(float4*)&bf_[8]  = *(const float4*)&Lb[t][jb + 8];
      *(float4*)&bf_[12] = *(const float4*)&Lb[t][jb + 12];
      *(float4*)&kf[0]  = *(const float4*)&Lk[t][jb + 0];
      *(float4*)&kf[4]  = *(const float4*)&Lk[t][jb + 4];
      *(float4*)&kf[8]  = *(const float4*)&Lk[t][jb + 8];
      *(float4*)&kf[12] = *(const float4*)&Lk[t][jb + 12];
      *(float4*)&rf[0]  = *(const float4*)&Lr[t][jb + 0];
      *(float4*)&rf[4]  = *(const float4*)&Lr[t][jb + 4];
      *(float4*)&rf[8]  = *(const float4*)&Lr[t][jb + 8];
      *(float4*)&rf[12] = *(const float4*)&Lr[t][jb + 12];
      float vi = Lv[t][il];
      float yp[16];
#pragma unroll
      for (int e = 0; e < 16; ++e) {
        float sn = S[e] * df[e] + sa * bf_[e] + vi * kf[e];
        S[e] = sn;
        yp[e] = sn * rf[e];
      }
#pragma unroll
      for (int st = 1; st < 16; st <<= 1)
#pragma unroll
        for (int e = 0; e < 16; e += 2 * st) yp[e] = yp[e] + yp[e + st];
      float ys = yp[0];
      float y = (ys + __shfl_xor(ys, 16)) + (__shfl_xor(ys, 32) + __shfl_xor(ys, 48));
      if (q == 0) yb[headbase + (size_t)(ch * 16 + t) * C_ + i0 + il] = y;
    }
  }
}

/* ---------------- GroupNorm(64/head) + bonus + gate -> bf16 A for final GEMM ---------------- */
__global__ void __launch_bounds__(256) gn_gg(
    const float* __restrict__ yb, const u16* __restrict__ bonus, const u16* __restrict__ gb,
    const float* __restrict__ gnw, const float* __restrict__ gnb,
    u16* __restrict__ ggb) {
  int rh = blockIdx.x * 4 + (threadIdx.x >> 6);
  int n = threadIdx.x & 63;
  int h = rh & (H_ - 1);
  size_t idx = (size_t)rh * 64 + n;
  int c = h * 64 + n;
  float y = yb[idx];
  float mu = wsum64(y) * (1.f / 64.f);
  float d = y - mu;
  float var = wsum64(d * d) * (1.f / 64.f);
  float yn = d * rsqrtf(var + 6.4e-4f) * gnw[c] + gnb[c];
  ggb[idx] = f2bf((yn + bf2f(bonus[idx])) * bf2f(gb[idx]));
}

extern "C" void kernel_launch(void* const* d_in, const int* in_sizes, int n_in,
                              void* d_out, int out_size, void* d_ws, size_t ws_size,
                              hipStream_t stream) {
  const float* x      = (const float*)d_in[0];
  const float* vfirst = (const float*)d_in[1];
  const float* x_r = (const float*)d_in[2];
  const float* x_w = (const float*)d_in[3];
  const float* x_k = (const float*)d_in[4];
  const float* x_v = (const float*)d_in[5];
  const float* x_a = (const float*)d_in[6];
  const float* x_g = (const float*)d_in[7];
  const float* w0  = (const float*)d_in[8];
  const float* w1  = (const float*)d_in[9];
  const float* w2  = (const float*)d_in[10];
  const float* a0  = (const float*)d_in[11];
  const float* a1  = (const float*)d_in[12];
  const float* a2  = (const float*)d_in[13];
  const float* v0  = (const float*)d_in[14];
  const float* v1  = (const float*)d_in[15];
  const float* v2  = (const float*)d_in[16];
  const float* g1  = (const float*)d_in[17];
  const float* g2  = (const float*)d_in[18];
  const float* k_k = (const float*)d_in[19];
  const float* k_a = (const float*)d_in[20];
  const float* r_k = (const float*)d_in[21];
  const float* W_r = (const float*)d_in[22];
  const float* W_k = (const float*)d_in[23];
  const float* W_v = (const float*)d_in[24];
  const float* W_o = (const float*)d_in[25];
  const float* gnw = (const float*)d_in[26];
  const float* gnb = (const float*)d_in[27];
  float* out = (float*)d_out;

  char* ws = (char*)d_ws;
  size_t off = 0;
  auto alloc = [&](size_t bytes) -> void* {
    void* p = ws + off;
    off += (bytes + 255) & ~(size_t)255;
    return p;
  };
  const size_t MCb2 = MC * 2;

  /* A-region: 6 contiguous 16MiB bf16 mix buffers, later reused */
  u16* xrb = (u16*)alloc(MCb2);   /* A0: xr -> dw_bf -> ggb            */
  u16* xwb = (u16*)alloc(MCb2);   /* A1: xw -> da_bf -> b_bf           */
  u16* xkb = (u16*)alloc(MCb2);   /* A2: xk -> dv_bf -> z_bf           */
  u16* xvb = (u16*)alloc(MCb2);   /* A3: xv -> g_bf                    */
  u16* xab = (u16*)alloc(MCb2);   /* A4: xa ┐                          */
  u16* xgb = (u16*)alloc(MCb2);   /* A5: xg ┘ -> yb fp32 (32MiB)       */
  u16* Wrb = (u16*)alloc((size_t)C_ * C_ * 2);
  u16* Wkb = (u16*)alloc((size_t)C_ * C_ * 2);
  u16* Wvb = (u16*)alloc((size_t)C_ * C_ * 2);
  u16* Wob = (u16*)alloc((size_t)C_ * C_ * 2);
  u16* w1t = (u16*)alloc((size_t)64 * C_ * 2);
  u16* a1t = (u16*)alloc((size_t)64 * C_ * 2);
  u16* v1t = (u16*)alloc((size_t)32 * C_ * 2);
  u16* g1t = (u16*)alloc((size_t)128 * C_ * 2);
  u16* w2t = (u16*)alloc((size_t)C_ * 64 * 2);
  u16* a2t = (u16*)alloc((size_t)C_ * 64 * 2);
  u16* v2t = (u16*)alloc((size_t)C_ * 32 * 2);
  u16* g2t = (u16*)alloc((size_t)C_ * 128 * 2);
  float* hw = (float*)alloc((size_t)M_ * 64 * 4);
  float* ha = (float*)alloc((size_t)M_ * 64 * 4);
  float* hv = (float*)alloc((size_t)M_ * 32 * 4);
  float* hg = (float*)alloc((size_t)M_ * 128 * 4);
  u16* hwb = (u16*)alloc((size_t)M_ * 64 * 2);
  u16* hab = (u16*)alloc((size_t)M_ * 64 * 2);
  u16* hvb = (u16*)alloc((size_t)M_ * 32 * 2);
  u16* hgb = (u16*)alloc((size_t)M_ * 128 * 2);
  u16* r_bf = (u16*)alloc(MCb2);            /* D0 */
  u16* k_bf = (u16*)alloc(MCb2);            /* D1: k -> k2 in place */
  u16* v_bf = (u16*)alloc(MCb2);            /* D2: v -> v2 in place */
  float* dec = (float*)alloc(MC * 4);       /* E0 fp32 */
  u16* bonus  = (u16*)alloc(MCb2);          /* E1 */
  /* aliases (regions dead at write time; see schedule) */
  u16* dw_bf = xrb;
  u16* da_bf = xwb;   /* then b_bf in place */
  u16* dv_bf = xkb;   /* then z_bf in place */
  u16* g_bf  = xvb;
  float* yb  = (float*)xab;  /* spans xab+xgb = 32 MiB */
  u16* ggb   = xrb;          /* after dw_bf consumed   */
  (void)ws_size; (void)in_sizes; (void)n_in; (void)out_size;

  dim3 blk(256);

  /* weight conversion */
  convbf8<<<(C_ * C_ / 8 + 255) / 256, blk, 0, stream>>>(W_r, Wrb, C_ * C_ / 8);
  convbf8<<<(C_ * C_ / 8 + 255) / 256, blk, 0, stream>>>(W_k, Wkb, C_ * C_ / 8);
  convbf8<<<(C_ * C_ / 8 + 255) / 256, blk, 0, stream>>>(W_v, Wvb, C_ * C_ / 8);
  convbf8<<<(C_ * C_ / 8 + 255) / 256, blk, 0, stream>>>(W_o, Wob, C_ * C_ / 8);
  tconvbf<<<(C_ * 64 + 255) / 256, blk, 0, stream>>>(w1, w1t, C_, 64);
  tconvbf<<<(C_ * 64 + 255) / 256, blk, 0, stream>>>(a1, a1t, C_, 64);
  tconvbf<<<(C_ * 32 + 255) / 256, blk, 0, stream>>>(v1, v1t, C_, 32);
  tconvbf<<<(C_ * 128 + 255) / 256, blk, 0, stream>>>(g1, g1t, C_, 128);
  tconvbf<<<(C_ * 64 + 255) / 256, blk, 0, stream>>>(w2, w2t, 64, C_);
  tconvbf<<<(C_ * 64 + 255) / 256, blk, 0, stream>>>(a2, a2t, 64, C_);
  tconvbf<<<(C_ * 32 + 255) / 256, blk, 0, stream>>>(v2, v2t, 32, C_);
  tconvbf<<<(C_ * 128 + 255) / 256, blk, 0, stream>>>(g2, g2t, 128, C_);

  /* time-shift mixes, v_first passthrough */
  prep_mix<<<(int)(MC / 8 / 256), blk, 0, stream>>>(x, x_r, x_w, x_k, x_v, x_a, x_g,
                                                    xrb, xwb, xkb, xvb, xab, xgb);
  hipMemcpyAsync(out + MC, vfirst, MC * sizeof(float), hipMemcpyDeviceToDevice, stream);

  /* big GEMMs: r, k, v (bf16 out) */
  dim3 g128(M_ / 128, C_ / 128);
  gemm128<true><<<g128, blk, 0, stream>>>(xrb, Wrb, r_bf, M_, C_, C_);
  gemm128<true><<<g128, blk, 0, stream>>>(xkb, Wkb, k_bf, M_, C_, C_);
  gemm128<true><<<g128, blk, 0, stream>>>(xvb, Wvb, v_bf, M_, C_, C_);

  /* LoRA stage-1 (fp32 out) */
  gemm_bn32<<<dim3(M_ / 128, 2), blk, 0, stream>>>(xwb, w1t, hw, M_, 64, C_);
  gemm_bn32<<<dim3(M_ / 128, 2), blk, 0, stream>>>(xab, a1t, ha, M_, 64, C_);
  gemm_bn32<<<dim3(M_ / 128, 1), blk, 0, stream>>>(xvb, v1t, hv, M_, 32, C_);
  gemm_bn32<<<dim3(M_ / 128, 4), blk, 0, stream>>>(xgb, g1t, hg, M_, 128, C_);

  /* activations + bf16 */
  act_conv<<<(M_ * 64 + 255) / 256, blk, 0, stream>>>(hw, hwb, M_ * 64, 0);
  act_conv<<<(M_ * 64 + 255) / 256, blk, 0, stream>>>(ha, hab, M_ * 64, 1);
  act_conv<<<(M_ * 32 + 255) / 256, blk, 0, stream>>>(hv, hvb, M_ * 32, 1);
  act_conv<<<(M_ * 128 + 255) / 256, blk, 0, stream>>>(hg, hgb, M_ * 128, 2);

  /* LoRA stage-2 (bf16 out, into dead mix regions) */
  gemm128<true><<<g128, blk, 0, stream>>>(hwb, w2t, dw_bf, M_, C_, 64);
  gemm128<true><<<g128, blk, 0, stream>>>(hab, a2t, da_bf, M_, C_, 64);
  gemm128<true><<<g128, blk, 0, stream>>>(hvb, v2t, dv_bf, M_, C_, 32);
  gemm128<true><<<g128, blk, 0, stream>>>(hgb, g2t, g_bf, M_, C_, 128);

  /* scan inputs (in-place bf16) + dec fp32 + bonus bf16 */
  scan_prep<<<M_ * H_ / 4, blk, 0, stream>>>(r_bf, k_bf, v_bf, dw_bf, da_bf, dv_bf, vfirst,
                                             a0, v0, w0, k_k, k_a, r_k, dec, bonus);

  /* sequential scan: 4 row-blocks per head, 256 blocks x 64 threads */
  rwkv_scan<<<dim3(B_ * H_ * 4), dim3(64), 0, stream>>>(r_bf, dec, k_bf, v_bf, dv_bf, da_bf, yb);

  /* GroupNorm + bonus + gate -> bf16 */
  gn_gg<<<M_ * H_ / 4, blk, 0, stream>>>(yb, bonus, g_bf, gnw, gnb, ggb);

  /* output projection (fp32 out) */
  gemm128<false><<<g128, blk, 0, stream>>>(ggb, Wob, out, M_, C_, C_);
}

// Round 6
// 1265.310 us; speedup vs baseline: 1.3132x; 1.0646x over previous
//
#include <hip/hip_runtime.h>
#include <stdint.h>

typedef unsigned short u16;
typedef unsigned int u32;

#define B_ 2
#define T_ 2048
#define C_ 2048
#define H_ 32
#define M_ (B_*T_)              /* 4096 rows */
static const size_t MC = (size_t)M_ * C_;   /* 8388608 */

typedef __attribute__((ext_vector_type(8))) short s16x8;
typedef __attribute__((ext_vector_type(4))) float f32x4;

__device__ __forceinline__ u16 f2bf(float f) {
  union { float f; u32 u; } v; v.f = f;
  u32 r = v.u + 0x7FFFu + ((v.u >> 16) & 1u);
  return (u16)(r >> 16);
}
__device__ __forceinline__ float bits2f(u32 u) {
  union { u32 u; float f; } v; v.u = u; return v.f;
}
__device__ __forceinline__ u32 f2bits(float f) {
  union { float f; u32 u; } v; v.f = f; return v.u;
}
__device__ __forceinline__ float bf2f(u16 h) { return bits2f(((u32)h) << 16); }
__device__ __forceinline__ float sigm(float x) { return 1.0f / (1.0f + expf(-x)); }

__device__ __forceinline__ float wsum64(float x) {
  x += __shfl_xor(x, 32);
  x += __shfl_xor(x, 16);
  x += __shfl_xor(x, 8);
  x += __shfl_xor(x, 4);
  x += __shfl_xor(x, 2);
  x += __shfl_xor(x, 1);
  return x;
}

/* 4-group reduce over lanes {l, l^16, l^32, l^48} — VALU permlane path (no LDS pipe). */
#if __has_builtin(__builtin_amdgcn_permlane16_swap) && __has_builtin(__builtin_amdgcn_permlane32_swap)
typedef __attribute__((ext_vector_type(2))) unsigned int u32x2;
__device__ __forceinline__ float preduce4(float s) {
  u32 su = f2bits(s);
  u32x2 p1 = __builtin_amdgcn_permlane16_swap(su, su, false, false);
  float s1 = bits2f(p1.x) + bits2f(p1.y);
  u32 s1u = f2bits(s1);
  u32x2 p2 = __builtin_amdgcn_permlane32_swap(s1u, s1u, false, false);
  return bits2f(p2.x) + bits2f(p2.y);
}
#else
__device__ __forceinline__ float preduce4(float s) {
  return (s + __shfl_xor(s, 16)) + (__shfl_xor(s, 32) + __shfl_xor(s, 48));
}
#endif

#define GL2LDS(g, l) __builtin_amdgcn_global_load_lds( \
    (const __attribute__((address_space(1))) u32*)(g), \
    (__attribute__((address_space(3))) u32*)(l), 16, 0, 0)

/* ---------------- bf16 NT GEMM, 128x128 tile, BK=32 (m97 structure) ----------------
   C[M,N] = A[M,K] * B[N,K]^T ; A,B bf16 row-major (lda=ldb=K); C bf16 or fp32. */
template<bool BF16OUT>
__global__ void __launch_bounds__(256) gemm128(const u16* __restrict__ A, const u16* __restrict__ Bm,
                                               void* __restrict__ Cvp, int M, int N, int K) {
  __shared__ u16 As[128 * 32];
  __shared__ u16 Bs[128 * 32];
  const int tid = threadIdx.x;
  const int w = tid >> 6, l = tid & 63;
  const int wm = w >> 1, wn = w & 1;
  const int bm = blockIdx.x, bn = blockIdx.y;

  const int row0 = tid >> 2, kq0 = tid & 3;
  const u16* ag0 = A + (size_t)(bm * 128 + row0) * K + kq0 * 8;
  const u16* ag1 = ag0 + (size_t)64 * K;
  const u16* bg0 = Bm + (size_t)(bn * 128 + row0) * K + kq0 * 8;
  const u16* bg1 = bg0 + (size_t)64 * K;
  u16* al0 = &As[w * 512];
  u16* al1 = &As[2048 + w * 512];
  u16* bl0 = &Bs[w * 512];
  u16* bl1 = &Bs[2048 + w * 512];

  const int lrow = l & 15, lko = (l >> 4) * 8;
  const u16* Ars = &As[(wm * 64 + lrow) * 32 + lko];
  const u16* Brs = &Bs[(wn * 64 + lrow) * 32 + lko];

  f32x4 acc[4][4] = {};

  for (int k0 = 0; k0 < K; k0 += 32) {
    __syncthreads();
    GL2LDS(ag0, al0); GL2LDS(ag1, al1);
    GL2LDS(bg0, bl0); GL2LDS(bg1, bl1);
    ag0 += 32; ag1 += 32; bg0 += 32; bg1 += 32;
    __syncthreads();
    s16x8 af[4], bf[4];
#pragma unroll
    for (int m = 0; m < 4; ++m) af[m] = *(const s16x8*)(Ars + m * 16 * 32);
#pragma unroll
    for (int n = 0; n < 4; ++n) bf[n] = *(const s16x8*)(Brs + n * 16 * 32);
#pragma unroll
    for (int m = 0; m < 4; ++m)
#pragma unroll
      for (int n = 0; n < 4; ++n)
        acc[m][n] = __builtin_amdgcn_mfma_f32_16x16x32_bf16(af[m], bf[n], acc[m][n], 0, 0, 0);
  }

  const int crow0 = bm * 128 + wm * 64 + (l >> 4) * 4;
  const int ccol0 = bn * 128 + wn * 64 + (l & 15);
  if constexpr (BF16OUT) {
    u16* Cm = (u16*)Cvp;
#pragma unroll
    for (int m = 0; m < 4; ++m)
#pragma unroll
      for (int rr = 0; rr < 4; ++rr) {
        const int row = crow0 + m * 16 + rr;
        u16* cp = Cm + (size_t)row * N + ccol0;
#pragma unroll
        for (int n = 0; n < 4; ++n) cp[n * 16] = f2bf(acc[m][n][rr]);
      }
  } else {
    float* Cm = (float*)Cvp;
#pragma unroll
    for (int m = 0; m < 4; ++m)
#pragma unroll
      for (int rr = 0; rr < 4; ++rr) {
        const int row = crow0 + m * 16 + rr;
        float* cp = Cm + (size_t)row * N + ccol0;
#pragma unroll
        for (int n = 0; n < 4; ++n) cp[n * 16] = acc[m][n][rr];
      }
  }
}

/* ---------------- bf16 NT GEMM, 128x32 tile (small-N stage-1 LoRA GEMMs), fp32 out ---------------- */
__global__ void __launch_bounds__(256) gemm_bn32(const u16* __restrict__ A, const u16* __restrict__ Bm,
                                                 float* __restrict__ Cm, int M, int N, int K) {
  __shared__ u16 As[128 * 32];
  __shared__ u16 Bs[32 * 32];
  const int tid = threadIdx.x;
  const int w = tid >> 6, l = tid & 63;
  const int bm = blockIdx.x, bn = blockIdx.y;

  const int row0 = tid >> 2, kq0 = tid & 3;
  const u16* ag0 = A + (size_t)(bm * 128 + row0) * K + kq0 * 8;
  const u16* ag1 = ag0 + (size_t)64 * K;
  u16* al0 = &As[w * 512];
  u16* al1 = &As[2048 + w * 512];

  const int bc = (w & 1) * 64 + l;  /* chunk id for B staging (waves 0,1) */
  const u16* bg0 = Bm + (size_t)(bn * 32 + (bc >> 2)) * K + (bc & 3) * 8;
  u16* bl0 = &Bs[(w & 1) * 512];

  const int lrow = l & 15, lko = (l >> 4) * 8;
  const u16* Ars = &As[(w * 32 + lrow) * 32 + lko];
  const u16* Brs = &Bs[lrow * 32 + lko];

  f32x4 acc[2][2] = {};
  for (int k0 = 0; k0 < K; k0 += 32) {
    __syncthreads();
    GL2LDS(ag0, al0); GL2LDS(ag1, al1);
    if (w < 2) GL2LDS(bg0, bl0);
    ag0 += 32; ag1 += 32; bg0 += 32;
    __syncthreads();
    s16x8 af[2], bf[2];
    af[0] = *(const s16x8*)(Ars);
    af[1] = *(const s16x8*)(Ars + 16 * 32);
    bf[0] = *(const s16x8*)(Brs);
    bf[1] = *(const s16x8*)(Brs + 16 * 32);
#pragma unroll
    for (int m = 0; m < 2; ++m)
#pragma unroll
      for (int n = 0; n < 2; ++n)
        acc[m][n] = __builtin_amdgcn_mfma_f32_16x16x32_bf16(af[m], bf[n], acc[m][n], 0, 0, 0);
  }
  const int crow0 = bm * 128 + w * 32 + (l >> 4) * 4;
  const int ccol0 = bn * 32 + (l & 15);
#pragma unroll
  for (int m = 0; m < 2; ++m)
#pragma unroll
    for (int rr = 0; rr < 4; ++rr) {
      const int row = crow0 + m * 16 + rr;
      float* cp = Cm + (size_t)row * N + ccol0;
      cp[0] = acc[m][0][rr];
      cp[16] = acc[m][1][rr];
    }
}

/* ---------------- time-shift + 6 token mixes -> bf16 A matrices ---------------- */
__global__ void __launch_bounds__(256) prep_mix(const float* __restrict__ x,
    const float* __restrict__ mr, const float* __restrict__ mw, const float* __restrict__ mk,
    const float* __restrict__ mv, const float* __restrict__ ma, const float* __restrict__ mg,
    u16* __restrict__ xrb, u16* __restrict__ xwb, u16* __restrict__ xkb,
    u16* __restrict__ xvb, u16* __restrict__ xab, u16* __restrict__ xgb) {
  int gid = blockIdx.x * 256 + threadIdx.x;   /* 0 .. MC/8 */
  int row = gid >> 8;
  int col = (gid & 255) << 3;
  size_t base = (size_t)row * C_ + col;
  float xv[8], dx[8];
  *(float4*)&xv[0] = *(const float4*)(x + base);
  *(float4*)&xv[4] = *(const float4*)(x + base + 4);
  if ((row & (T_ - 1)) == 0) {
#pragma unroll
    for (int j = 0; j < 8; ++j) dx[j] = -xv[j];
  } else {
    float xp[8];
    *(float4*)&xp[0] = *(const float4*)(x + base - C_);
    *(float4*)&xp[4] = *(const float4*)(x + base - C_ + 4);
#pragma unroll
    for (int j = 0; j < 8; ++j) dx[j] = xp[j] - xv[j];
  }
#define EMIT(dst, mixp) { \
    float4 m0 = *(const float4*)(mixp + col); \
    float4 m1 = *(const float4*)(mixp + col + 4); \
    float o0 = xv[0] + dx[0] * m0.x, o1 = xv[1] + dx[1] * m0.y; \
    float o2 = xv[2] + dx[2] * m0.z, o3 = xv[3] + dx[3] * m0.w; \
    float o4 = xv[4] + dx[4] * m1.x, o5 = xv[5] + dx[5] * m1.y; \
    float o6 = xv[6] + dx[6] * m1.z, o7 = xv[7] + dx[7] * m1.w; \
    uint4 pk; \
    pk.x = (u32)f2bf(o0) | ((u32)f2bf(o1) << 16); \
    pk.y = (u32)f2bf(o2) | ((u32)f2bf(o3) << 16); \
    pk.z = (u32)f2bf(o4) | ((u32)f2bf(o5) << 16); \
    pk.w = (u32)f2bf(o6) | ((u32)f2bf(o7) << 16); \
    *(uint4*)(dst + base) = pk; }
  EMIT(xrb, mr) EMIT(xwb, mw) EMIT(xkb, mk) EMIT(xvb, mv) EMIT(xab, ma) EMIT(xgb, mg)
#undef EMIT
}

/* ---------------- fp32 -> bf16 (8 elems/thread) ---------------- */
__global__ void __launch_bounds__(256) convbf8(const float* __restrict__ in, u16* __restrict__ out, int n8) {
  int gid = blockIdx.x * 256 + threadIdx.x;
  if (gid >= n8) return;
  size_t b = (size_t)gid * 8;
  float4 a0 = *(const float4*)(in + b), a1 = *(const float4*)(in + b + 4);
  uint4 pk;
  pk.x = (u32)f2bf(a0.x) | ((u32)f2bf(a0.y) << 16);
  pk.y = (u32)f2bf(a0.z) | ((u32)f2bf(a0.w) << 16);
  pk.z = (u32)f2bf(a1.x) | ((u32)f2bf(a1.y) << 16);
  pk.w = (u32)f2bf(a1.z) | ((u32)f2bf(a1.w) << 16);
  *(uint4*)(out + b) = pk;
}

/* ---------------- transpose + bf16 convert: in[R][Cc] -> out[Cc][R] ---------------- */
__global__ void __launch_bounds__(256) tconvbf(const float* __restrict__ in, u16* __restrict__ out, int R, int Cc) {
  int gid = blockIdx.x * 256 + threadIdx.x;
  if (gid >= R * Cc) return;
  int i = gid % R, j = gid / R;
  out[gid] = f2bf(in[(size_t)i * Cc + j]);
}

/* ---------------- activation + bf16 convert (mode 0=tanh,1=id,2=sigmoid) ---------------- */
__global__ void __launch_bounds__(256) act_conv(const float* __restrict__ in, u16* __restrict__ out, int n, int mode) {
  int gid = blockIdx.x * 256 + threadIdx.x;
  if (gid >= n) return;
  float v = in[gid];
  if (mode == 0) v = tanhf(v);
  else if (mode == 2) v = sigm(v);
  out[gid] = f2bf(v);
}

/* ---------------- scan-prep: decay, kk-norm, k', v-blend, z, b, bonus ----------------
   In-place per-element updates (each thread owns idx; all reads precede writes).
   dec stays fp32 (bf16 decay costs ~0.06 absmax). */
__global__ void __launch_bounds__(256) scan_prep(
    const u16* __restrict__ rb, u16* __restrict__ kb, u16* __restrict__ vb,
    const u16* __restrict__ dwb, u16* __restrict__ dab, u16* __restrict__ dvbb,
    const float* __restrict__ v_first,
    const float* __restrict__ a0, const float* __restrict__ v0, const float* __restrict__ w0,
    const float* __restrict__ k_k, const float* __restrict__ k_a, const float* __restrict__ r_k,
    float* __restrict__ dec, u16* __restrict__ bonus) {
  int rh = blockIdx.x * 4 + (threadIdx.x >> 6);
  int n = threadIdx.x & 63;
  int h = rh & (H_ - 1);
  size_t idx = (size_t)rh * 64 + n;
  int c = h * 64 + n;
  float kv = bf2f(kb[idx]), dav = bf2f(dab[idx]), dwv = bf2f(dwb[idx]);
  float dvv = bf2f(dvbb[idx]), vv = bf2f(vb[idx]);
  float vf = v_first[idx], rv = bf2f(rb[idx]);
  float av = sigm(a0[c] + dav);
  float kkv = kv * k_k[c];
  float ss = wsum64(kkv * kkv);
  float kkn = kkv / fmaxf(sqrtf(ss), 1e-12f);
  float k2 = kv * (1.f + (av - 1.f) * k_a[c]);
  float w_ = w0[c] + dwv;
  float wl = -log1pf(expf(-w_)) - 0.5f;
  float decf = expf(-expf(wl));
  float sv = sigm(v0[c] + dvv);
  float v2 = vv + (vf - vv) * sv;
  float bp = wsum64(rv * k2 * r_k[c]);
  kb[idx] = f2bf(k2);
  vb[idx] = f2bf(v2);
  dab[idx] = f2bf(kkn * av);   /* b */
  dvbb[idx] = f2bf(-kkn);      /* z */
  dec[idx] = decf;
  bonus[idx] = f2bf(bp * v2);
}

/* ---------------- RWKV7 sequential scan: 4 blocks per (b,h), 16 rows each ----------------
   256 blocks x 64 threads (1 wave). Lane = (row il = l&15, j-quarter q = l>>4).
   fp32 LDS (padded rows), b128 reads, pairwise trees, permlane VALU reduces. */
__device__ __forceinline__ void unpk8(u32 a, u32 b, u32 c, u32 d, float* o) {
  o[0] = bits2f(a << 16); o[1] = bits2f(a & 0xffff0000u);
  o[2] = bits2f(b << 16); o[3] = bits2f(b & 0xffff0000u);
  o[4] = bits2f(c << 16); o[5] = bits2f(c & 0xffff0000u);
  o[6] = bits2f(d << 16); o[7] = bits2f(d & 0xffff0000u);
}

__global__ void __launch_bounds__(64) rwkv_scan(
    const u16* __restrict__ rb, const float* __restrict__ decb, const u16* __restrict__ kb,
    const u16* __restrict__ vb, const u16* __restrict__ zb, const u16* __restrict__ bbuf,
    float* __restrict__ yb) {
  __shared__ float Lr[16][68], Ld[16][68], Lk[16][68], Lz[16][68], Lb[16][68];
  __shared__ float Lv[16][20];
  const int tid = threadIdx.x;           /* 0..63 */
  const int il = tid & 15;               /* local row */
  const int q = tid >> 4;                /* j-quarter */
  const int bh = blockIdx.x >> 2;        /* 0..63 */
  const int rblk = blockIdx.x & 3;
  const int bbx = bh >> 5, h = bh & 31;
  const int i0 = rblk * 16;
  const size_t headbase = ((size_t)bbx * T_ * H_ + h) * 64;

  /* staging slot: thread loads 16 elems of one step for shared arrays, 4 v-elems */
  const int pt = tid >> 2;               /* step 0..15 */
  const int pc = (tid & 3) * 16;         /* col base */
  const size_t poff = headbase + (size_t)pt * C_ + pc;
  const size_t voff = headbase + (size_t)pt * C_ + i0 + (tid & 3) * 4;

  float S[16];
#pragma unroll
  for (int e = 0; e < 16; ++e) S[e] = 0.f;

  uint4 pr0, pr1, pk0, pk1, pz0, pz1, pb0, pb1;
  float4 pd0, pd1, pd2, pd3;
  uint2 pv;
  pr0 = *(const uint4*)(rb + poff);   pr1 = *(const uint4*)(rb + poff + 8);
  pk0 = *(const uint4*)(kb + poff);   pk1 = *(const uint4*)(kb + poff + 8);
  pz0 = *(const uint4*)(zb + poff);   pz1 = *(const uint4*)(zb + poff + 8);
  pb0 = *(const uint4*)(bbuf + poff); pb1 = *(const uint4*)(bbuf + poff + 8);
  pd0 = *(const float4*)(decb + poff);     pd1 = *(const float4*)(decb + poff + 4);
  pd2 = *(const float4*)(decb + poff + 8); pd3 = *(const float4*)(decb + poff + 12);
  pv  = *(const uint2*)(vb + voff);

  for (int ch = 0; ch < T_ / 16; ++ch) {
    __syncthreads();
    {
      float f[16];
      unpk8(pr0.x, pr0.y, pr0.z, pr0.w, f); unpk8(pr1.x, pr1.y, pr1.z, pr1.w, f + 8);
      *(float4*)&Lr[pt][pc + 0] = *(float4*)&f[0];  *(float4*)&Lr[pt][pc + 4] = *(float4*)&f[4];
      *(float4*)&Lr[pt][pc + 8] = *(float4*)&f[8];  *(float4*)&Lr[pt][pc + 12] = *(float4*)&f[12];
      unpk8(pk0.x, pk0.y, pk0.z, pk0.w, f); unpk8(pk1.x, pk1.y, pk1.z, pk1.w, f + 8);
      *(float4*)&Lk[pt][pc + 0] = *(float4*)&f[0];  *(float4*)&Lk[pt][pc + 4] = *(float4*)&f[4];
      *(float4*)&Lk[pt][pc + 8] = *(float4*)&f[8];  *(float4*)&Lk[pt][pc + 12] = *(float4*)&f[12];
      unpk8(pz0.x, pz0.y, pz0.z, pz0.w, f); unpk8(pz1.x, pz1.y, pz1.z, pz1.w, f + 8);
      *(float4*)&Lz[pt][pc + 0] = *(float4*)&f[0];  *(float4*)&Lz[pt][pc + 4] = *(float4*)&f[4];
      *(float4*)&Lz[pt][pc + 8] = *(float4*)&f[8];  *(float4*)&Lz[pt][pc + 12] = *(float4*)&f[12];
      unpk8(pb0.x, pb0.y, pb0.z, pb0.w, f); unpk8(pb1.x, pb1.y, pb1.z, pb1.w, f + 8);
      *(float4*)&Lb[pt][pc + 0] = *(float4*)&f[0];  *(float4*)&Lb[pt][pc + 4] = *(float4*)&f[4];
      *(float4*)&Lb[pt][pc + 8] = *(float4*)&f[8];  *(float4*)&Lb[pt][pc + 12] = *(float4*)&f[12];
      *(float4*)&Ld[pt][pc + 0] = pd0;  *(float4*)&Ld[pt][pc + 4] = pd1;
      *(float4*)&Ld[pt][pc + 8] = pd2;  *(float4*)&Ld[pt][pc + 12] = pd3;
      float g[4];
      g[0] = bits2f(pv.x << 16); g[1] = bits2f(pv.x & 0xffff0000u);
      g[2] = bits2f(pv.y << 16); g[3] = bits2f(pv.y & 0xffff0000u);
      *(float4*)&Lv[pt][(tid & 3) * 4] = *(float4*)&g[0];
    }
    __syncthreads();
    if (ch + 1 < T_ / 16) {
      size_t o2 = poff + (size_t)(ch + 1) * 16 * C_;
      size_t v2 = voff + (size_t)(ch + 1) * 16 * C_;
      pr0 = *(const uint4*)(rb + o2);   pr1 = *(const uint4*)(rb + o2 + 8);
      pk0 = *(const uint4*)(kb + o2);   pk1 = *(const uint4*)(kb + o2 + 8);
      pz0 = *(const uint4*)(zb + o2);   pz1 = *(const uint4*)(zb + o2 + 8);
      pb0 = *(const uint4*)(bbuf + o2); pb1 = *(const uint4*)(bbuf + o2 + 8);
      pd0 = *(const float4*)(decb + o2);     pd1 = *(const float4*)(decb + o2 + 4);
      pd2 = *(const float4*)(decb + o2 + 8); pd3 = *(const float4*)(decb + o2 + 12);
      pv  = *(const uint2*)(vb + v2);
    }
#pragma unroll
    for (int t = 0; t < 16; ++t) {
      const int jb = q * 16;
      /* --- sa partial: z-slice, products, pairwise tree, permlane reduce --- */
      float zf[16];
      *(float4*)&zf[0]  = *(const float4*)&Lz[t][jb + 0];
      *(float4*)&zf[4]  = *(const float4*)&Lz[t][jb + 4];
      *(float4*)&zf[8]  = *(const float4*)&Lz[t][jb + 8];
      *(float4*)&zf[12] = *(const float4*)&Lz[t][jb + 12];
      float m[16];
#pragma unroll
      for (int e = 0; e < 16; ++e) m[e] = S[e] * zf[e];
#pragma unroll
      for (int st = 1; st < 16; st <<= 1)
#pragma unroll
        for (int e = 0; e < 16; e += 2 * st) m[e] = m[e] + m[e + st];
      float sa = preduce4(m[0]);

      /* --- update + y --- */
      float df[16], bf_[16], kf[16], rf[16];
      *(float4*)&df[0]  = *(const float4*)&Ld[t][jb + 0];
      *(float4*)&df[4]  = *(const float4*)&Ld[t][jb + 4];
      *(float4*)&df[8]  = *(const float4*)&Ld[t][jb + 8];
      *(float4*)&df[12] = *(const float4*)&Ld[t][jb + 12];
      *(float4*)&bf_[0]  = *(const float4*)&Lb[t][jb + 0];
      *(float4*)&bf_[4]  = *(const float4*)&Lb[t][jb + 4];
      *(float4*)&bf_[8]  = *(const float4*)&Lb[t][jb + 8];
      *(float4*)&bf_[12] = *(const float4*)&Lb[t][jb + 12];
      *(float4*)&kf[0]  = *(const float4*)&Lk[t][jb + 0];
      *(float4*)&kf[4]  = *(const float4*)&Lk[t][jb + 4];
      *(float4*)&kf[8]  = *(const float4*)&Lk[t][jb + 8];
      *(float4*)&kf[12] = *(const float4*)&Lk[t][jb + 12];
      *(float4*)&rf[0]  = *(const float4*)&Lr[t][jb + 0];
      *(float4*)&rf[4]  = *(const float4*)&Lr[t][jb + 4];
      *(float4*)&rf[8]  = *(const float4*)&Lr[t][jb + 8];
      *(float4*)&rf[12] = *(const float4*)&Lr[t][jb + 12];
      float vi = Lv[t][il];
      float yp[16];
#pragma unroll
      for (int e = 0; e < 16; ++e) {
        float sn = S[e] * df[e] + sa * bf_[e] + vi * kf[e];
        S[e] = sn;
        yp[e] = sn * rf[e];
      }
#pragma unroll
      for (int st = 1; st < 16; st <<= 1)
#pragma unroll
        for (int e = 0; e < 16; e += 2 * st) yp[e] = yp[e] + yp[e + st];
      float y = preduce4(yp[0]);
      if (q == 0) yb[headbase + (size_t)(ch * 16 + t) * C_ + i0 + il] = y;
    }
  }
}

/* ---------------- GroupNorm(64/head) + bonus + gate -> bf16 A for final GEMM ---------------- */
__global__ void __launch_bounds__(256) gn_gg(
    const float* __restrict__ yb, const u16* __restrict__ bonus, const u16* __restrict__ gb,
    const float* __restrict__ gnw, const float* __restrict__ gnb,
    u16* __restrict__ ggb) {
  int rh = blockIdx.x * 4 + (threadIdx.x >> 6);
  int n = threadIdx.x & 63;
  int h = rh & (H_ - 1);
  size_t idx = (size_t)rh * 64 + n;
  int c = h * 64 + n;
  float y = yb[idx];
  float mu = wsum64(y) * (1.f / 64.f);
  float d = y - mu;
  float var = wsum64(d * d) * (1.f / 64.f);
  float yn = d * rsqrtf(var + 6.4e-4f) * gnw[c] + gnb[c];
  ggb[idx] = f2bf((yn + bf2f(bonus[idx])) * bf2f(gb[idx]));
}

extern "C" void kernel_launch(void* const* d_in, const int* in_sizes, int n_in,
                              void* d_out, int out_size, void* d_ws, size_t ws_size,
                              hipStream_t stream) {
  const float* x      = (const float*)d_in[0];
  const float* vfirst = (const float*)d_in[1];
  const float* x_r = (const float*)d_in[2];
  const float* x_w = (const float*)d_in[3];
  const float* x_k = (const float*)d_in[4];
  const float* x_v = (const float*)d_in[5];
  const float* x_a = (const float*)d_in[6];
  const float* x_g = (const float*)d_in[7];
  const float* w0  = (const float*)d_in[8];
  const float* w1  = (const float*)d_in[9];
  const float* w2  = (const float*)d_in[10];
  const float* a0  = (const float*)d_in[11];
  const float* a1  = (const float*)d_in[12];
  const float* a2  = (const float*)d_in[13];
  const float* v0  = (const float*)d_in[14];
  const float* v1  = (const float*)d_in[15];
  const float* v2  = (const float*)d_in[16];
  const float* g1  = (const float*)d_in[17];
  const float* g2  = (const float*)d_in[18];
  const float* k_k = (const float*)d_in[19];
  const float* k_a = (const float*)d_in[20];
  const float* r_k = (const float*)d_in[21];
  const float* W_r = (const float*)d_in[22];
  const float* W_k = (const float*)d_in[23];
  const float* W_v = (const float*)d_in[24];
  const float* W_o = (const float*)d_in[25];
  const float* gnw = (const float*)d_in[26];
  const float* gnb = (const float*)d_in[27];
  float* out = (float*)d_out;

  char* ws = (char*)d_ws;
  size_t off = 0;
  auto alloc = [&](size_t bytes) -> void* {
    void* p = ws + off;
    off += (bytes + 255) & ~(size_t)255;
    return p;
  };
  const size_t MCb2 = MC * 2;

  /* A-region: 6 contiguous 16MiB bf16 mix buffers, later reused */
  u16* xrb = (u16*)alloc(MCb2);   /* A0: xr -> dw_bf -> ggb            */
  u16* xwb = (u16*)alloc(MCb2);   /* A1: xw -> da_bf -> b_bf           */
  u16* xkb = (u16*)alloc(MCb2);   /* A2: xk -> dv_bf -> z_bf           */
  u16* xvb = (u16*)alloc(MCb2);   /* A3: xv -> g_bf                    */
  u16* xab = (u16*)alloc(MCb2);   /* A4: xa ┐                          */
  u16* xgb = (u16*)alloc(MCb2);   /* A5: xg ┘ -> yb fp32 (32MiB)       */
  u16* Wrb = (u16*)alloc((size_t)C_ * C_ * 2);
  u16* Wkb = (u16*)alloc((size_t)C_ * C_ * 2);
  u16* Wvb = (u16*)alloc((size_t)C_ * C_ * 2);
  u16* Wob = (u16*)alloc((size_t)C_ * C_ * 2);
  u16* w1t = (u16*)alloc((size_t)64 * C_ * 2);
  u16* a1t = (u16*)alloc((size_t)64 * C_ * 2);
  u16* v1t = (u16*)alloc((size_t)32 * C_ * 2);
  u16* g1t = (u16*)alloc((size_t)128 * C_ * 2);
  u16* w2t = (u16*)alloc((size_t)C_ * 64 * 2);
  u16* a2t = (u16*)alloc((size_t)C_ * 64 * 2);
  u16* v2t = (u16*)alloc((size_t)C_ * 32 * 2);
  u16* g2t = (u16*)alloc((size_t)C_ * 128 * 2);
  float* hw = (float*)alloc((size_t)M_ * 64 * 4);
  float* ha = (float*)alloc((size_t)M_ * 64 * 4);
  float* hv = (float*)alloc((size_t)M_ * 32 * 4);
  float* hg = (float*)alloc((size_t)M_ * 128 * 4);
  u16* hwb = (u16*)alloc((size_t)M_ * 64 * 2);
  u16* hab = (u16*)alloc((size_t)M_ * 64 * 2);
  u16* hvb = (u16*)alloc((size_t)M_ * 32 * 2);
  u16* hgb = (u16*)alloc((size_t)M_ * 128 * 2);
  u16* r_bf = (u16*)alloc(MCb2);            /* D0 */
  u16* k_bf = (u16*)alloc(MCb2);            /* D1: k -> k2 in place */
  u16* v_bf = (u16*)alloc(MCb2);            /* D2: v -> v2 in place */
  float* dec = (float*)alloc(MC * 4);       /* E0 fp32 */
  u16* bonus  = (u16*)alloc(MCb2);          /* E1 */
  /* aliases (regions dead at write time; see schedule) */
  u16* dw_bf = xrb;
  u16* da_bf = xwb;   /* then b_bf in place */
  u16* dv_bf = xkb;   /* then z_bf in place */
  u16* g_bf  = xvb;
  float* yb  = (float*)xab;  /* spans xab+xgb = 32 MiB */
  u16* ggb   = xrb;          /* after dw_bf consumed   */
  (void)ws_size; (void)in_sizes; (void)n_in; (void)out_size;

  dim3 blk(256);

  /* weight conversion */
  convbf8<<<(C_ * C_ / 8 + 255) / 256, blk, 0, stream>>>(W_r, Wrb, C_ * C_ / 8);
  convbf8<<<(C_ * C_ / 8 + 255) / 256, blk, 0, stream>>>(W_k, Wkb, C_ * C_ / 8);
  convbf8<<<(C_ * C_ / 8 + 255) / 256, blk, 0, stream>>>(W_v, Wvb, C_ * C_ / 8);
  convbf8<<<(C_ * C_ / 8 + 255) / 256, blk, 0, stream>>>(W_o, Wob, C_ * C_ / 8);
  tconvbf<<<(C_ * 64 + 255) / 256, blk, 0, stream>>>(w1, w1t, C_, 64);
  tconvbf<<<(C_ * 64 + 255) / 256, blk, 0, stream>>>(a1, a1t, C_, 64);
  tconvbf<<<(C_ * 32 + 255) / 256, blk, 0, stream>>>(v1, v1t, C_, 32);
  tconvbf<<<(C_ * 128 + 255) / 256, blk, 0, stream>>>(g1, g1t, C_, 128);
  tconvbf<<<(C_ * 64 + 255) / 256, blk, 0, stream>>>(w2, w2t, 64, C_);
  tconvbf<<<(C_ * 64 + 255) / 256, blk, 0, stream>>>(a2, a2t, 64, C_);
  tconvbf<<<(C_ * 32 + 255) / 256, blk, 0, stream>>>(v2, v2t, 32, C_);
  tconvbf<<<(C_ * 128 + 255) / 256, blk, 0, stream>>>(g2, g2t, 128, C_);

  /* time-shift mixes, v_first passthrough */
  prep_mix<<<(int)(MC / 8 / 256), blk, 0, stream>>>(x, x_r, x_w, x_k, x_v, x_a, x_g,
                                                    xrb, xwb, xkb, xvb, xab, xgb);
  hipMemcpyAsync(out + MC, vfirst, MC * sizeof(float), hipMemcpyDeviceToDevice, stream);

  /* big GEMMs: r, k, v (bf16 out) */
  dim3 g128(M_ / 128, C_ / 128);
  gemm128<true><<<g128, blk, 0, stream>>>(xrb, Wrb, r_bf, M_, C_, C_);
  gemm128<true><<<g128, blk, 0, stream>>>(xkb, Wkb, k_bf, M_, C_, C_);
  gemm128<true><<<g128, blk, 0, stream>>>(xvb, Wvb, v_bf, M_, C_, C_);

  /* LoRA stage-1 (fp32 out) */
  gemm_bn32<<<dim3(M_ / 128, 2), blk, 0, stream>>>(xwb, w1t, hw, M_, 64, C_);
  gemm_bn32<<<dim3(M_ / 128, 2), blk, 0, stream>>>(xab, a1t, ha, M_, 64, C_);
  gemm_bn32<<<dim3(M_ / 128, 1), blk, 0, stream>>>(xvb, v1t, hv, M_, 32, C_);
  gemm_bn32<<<dim3(M_ / 128, 4), blk, 0, stream>>>(xgb, g1t, hg, M_, 128, C_);

  /* activations + bf16 */
  act_conv<<<(M_ * 64 + 255) / 256, blk, 0, stream>>>(hw, hwb, M_ * 64, 0);
  act_conv<<<(M_ * 64 + 255) / 256, blk, 0, stream>>>(ha, hab, M_ * 64, 1);
  act_conv<<<(M_ * 32 + 255) / 256, blk, 0, stream>>>(hv, hvb, M_ * 32, 1);
  act_conv<<<(M_ * 128 + 255) / 256, blk, 0, stream>>>(hg, hgb, M_ * 128, 2);

  /* LoRA stage-2 (bf16 out, into dead mix regions) */
  gemm128<true><<<g128, blk, 0, stream>>>(hwb, w2t, dw_bf, M_, C_, 64);
  gemm128<true><<<g128, blk, 0, stream>>>(hab, a2t, da_bf, M_, C_, 64);
  gemm128<true><<<g128, blk, 0, stream>>>(hvb, v2t, dv_bf, M_, C_, 32);
  gemm128<true><<<g128, blk, 0, stream>>>(hgb, g2t, g_bf, M_, C_, 128);

  /* scan inputs (in-place bf16) + dec fp32 + bonus bf16 */
  scan_prep<<<M_ * H_ / 4, blk, 0, stream>>>(r_bf, k_bf, v_bf, dw_bf, da_bf, dv_bf, vfirst,
                                             a0, v0, w0, k_k, k_a, r_k, dec, bonus);

  /* sequential scan: 4 row-blocks per head, 256 blocks x 64 threads */
  rwkv_scan<<<dim3(B_ * H_ * 4), dim3(64), 0, stream>>>(r_bf, dec, k_bf, v_bf, dv_bf, da_bf, yb);

  /* GroupNorm + bonus + gate -> bf16 */
  gn_gg<<<M_ * H_ / 4, blk, 0, stream>>>(yb, bonus, g_bf, gnw, gnb, ggb);

  /* output projection (fp32 out) */
  gemm128<false><<<g128, blk, 0, stream>>>(ggb, Wob, out, M_, C_, C_);
}